// Round 15
// baseline (477.803 us; speedup 1.0000x reference)
//
#include <hip/hip_runtime.h>
#include <hip/hip_bf16.h>

constexpr int NQ = 10000, NV = 19560, CAMS = 6, EMBED = 256, HEADS = 8,
              HEAD_DIM = 32, LEVELS = 4, POINTS = 8;
constexpr int MQ_PAD = 10112;          // 79 * 128
constexpr int MV_PAD = 117376;         // 917 * 128
constexpr int NBUCK = CAMS * 128;      // 16x8 tiles per cam
constexpr int MAXITEMS = CAMS * NQ * 4;

typedef unsigned int u32;
typedef unsigned short u16;
typedef unsigned char u8;
typedef __attribute__((ext_vector_type(8))) short short8v;
typedef __attribute__((ext_vector_type(4))) float f32x4;
typedef __attribute__((ext_vector_type(2))) float f32x2;

__device__ inline u16 f2bf(float f) {
  __hip_bfloat16 b = __float2bfloat16(f);
  return *(u16*)&b;
}
__device__ inline float bf2f(u16 v) { union { u32 i; float f; } x; x.i = (u32)v << 16; return x.f; }

// ---------------- fp32 -> bf16 row-padded convert (optional fused add) ----------------
__global__ void conv_bf16_kernel(const float* __restrict__ a, const float* __restrict__ b,
                                 u16* __restrict__ dst, int M, int Mpad) {
  int i = blockIdx.x * blockDim.x + threadIdx.x;
  if (i >= Mpad * 32) return;
  int row = i >> 5;
  int col = (i & 31) * 8;
  u16 o[8];
  if (row < M) {
    const float* pa = a + (size_t)row * 256 + col;
#pragma unroll
    for (int j = 0; j < 8; ++j) {
      float v = pa[j];
      if (b) v += b[(size_t)row * 256 + col + j];
      o[j] = f2bf(v);
    }
  } else {
#pragma unroll
    for (int j = 0; j < 8; ++j) o[j] = 0;
  }
  *(short8v*)&dst[(size_t)row * 256 + col] = *(short8v*)o;
}

// ---------------- plain weight transpose: src (K=256, N) -> dst (N, 256) bf16 ----------------
__global__ void transpose_w_kernel(const float* __restrict__ src, u16* __restrict__ dst, int N) {
  int g = blockIdx.x * blockDim.x + threadIdx.x;
  if (g >= N * 256) return;
  int n = g >> 8, k = g & 255;
  dst[(size_t)n * 256 + k] = f2bf(src[(size_t)k * N + n]);
}

// ------- permuted transpose for WqT (z-major output cols) + permuted catb -------
__device__ inline int orig_off_col(int j) {          // j in [0,512)
  int z = (j >> 7) & 3, h = (j >> 4) & 7, l = (j >> 2) & 3, pi = (j >> 1) & 1, xy = j & 1;
  return h * 64 + l * 16 + (z + 4 * pi) * 2 + xy;
}
__device__ inline int orig_att_col(int j) {          // j in [0,256)
  int z = (j >> 6) & 3, h = (j >> 3) & 7, l = (j >> 1) & 3, pi = j & 1;
  return h * 32 + l * 8 + (z + 4 * pi);
}
__global__ void transpose_wq_kernel(const float* __restrict__ Woff, const float* __restrict__ Watt,
                                    const float* __restrict__ boff, const float* __restrict__ batt,
                                    u16* __restrict__ WqT, float* __restrict__ catb) {
  int g = blockIdx.x * blockDim.x + threadIdx.x;
  if (g >= 768 * 256) return;
  int j = g >> 8, k = g & 255;
  float v;
  if (j < 512) v = Woff[(size_t)k * 512 + orig_off_col(j)];
  else         v = Watt[(size_t)k * 256 + orig_att_col(j - 512)];
  WqT[(size_t)j * 256 + k] = f2bf(v);
  if (k == 0) catb[j] = (j < 512) ? boff[orig_off_col(j)] : batt[orig_att_col(j - 512)];
}

// ---------------- bucket key ----------------
__device__ inline int buck_key(int c, float rx, float ry) {
  int tx = min(max((int)(rx * 16.f), 0), 15);
  int ty = min(max((int)(ry * 8.f), 0), 7);
  return c * 128 + ty * 16 + tx;
}

// ---------------- per-(cam,q) mask + 1/count + fused histogram ----------------
__global__ void mask_kernel(const int* __restrict__ bev, const float* __restrict__ ref,
                            unsigned char* __restrict__ m, float* __restrict__ cinv,
                            u32* __restrict__ hist) {
  int q = blockIdx.x * blockDim.x + threadIdx.x;
  if (q >= NQ) return;
  int cnt = 0;
  for (int c = 0; c < CAMS; ++c) {
    int any = 0;
    for (int z = 0; z < 4; ++z) any |= bev[((size_t)c * NQ + q) * 4 + z];
    m[c * NQ + q] = (unsigned char)(any != 0);
    cnt += (any != 0);
    if (any) {
      const float* rc = ref + ((size_t)c * NQ + q) * 8;
#pragma unroll
      for (int z = 0; z < 4; ++z)
        atomicAdd(&hist[buck_key(c, rc[z * 2], rc[z * 2 + 1])], 1u);
    }
  }
  cinv[q] = 1.0f / (float)(cnt > 0 ? cnt : 1);
}

// ---------------- exclusive scan over NBUCK buckets (one block) ----------------
__global__ void scan_kernel(const u32* __restrict__ hist, u32* __restrict__ cursor,
                            u32* __restrict__ total) {
  __shared__ u32 tmp[NBUCK];
  int t = threadIdx.x;
  u32 v = hist[t];
  tmp[t] = v;
  __syncthreads();
  for (int d = 1; d < NBUCK; d <<= 1) {
    u32 add = (t >= d) ? tmp[t - d] : 0;
    __syncthreads();
    tmp[t] += add;
    __syncthreads();
  }
  cursor[t] = tmp[t] - v;   // exclusive
  if (t == NBUCK - 1) *total = tmp[t];
}

// ---------------- scatter items into perm (sorted by bucket) ----------------
__global__ void scatter_kernel(const float* __restrict__ ref, const unsigned char* __restrict__ m,
                               u32* __restrict__ cursor, u32* __restrict__ perm) {
  int q = blockIdx.x * blockDim.x + threadIdx.x;
  if (q >= NQ) return;
  for (int c = 0; c < CAMS; ++c) {
    if (!m[c * NQ + q]) continue;
    const float* rc = ref + ((size_t)c * NQ + q) * 8;
#pragma unroll
    for (int z = 0; z < 4; ++z) {
      u32 pos = atomicAdd(&cursor[buck_key(c, rc[z * 2], rc[z * 2 + 1])], 1u);
      perm[pos] = ((u32)c << 16) | ((u32)z << 14) | (u32)q;
    }
  }
}

// ---------------- bf16 MFMA GEMM (128x128 tile, 256 thr) ----------------
// mode 0: fp32 out. mode 2: fp32 out + add. mode 3: coalesced split.
__global__ __launch_bounds__(256) void gemm_mfma(
    const u16* __restrict__ A, const u16* __restrict__ Bt,
    const float* __restrict__ bias, const float* __restrict__ add,
    void* __restrict__ Cout, void* __restrict__ Cout2, int M, int N, int mode) {
  constexpr int K = 256, BK = 64;
  __shared__ u16 As[128 * BK];
  __shared__ u16 Bs[128 * BK];
  const int tid = threadIdx.x;
  const int lane = tid & 63, w = tid >> 6;
  const int wr = w >> 1, wc = w & 1;
  const int row0 = blockIdx.y * 128, col0 = blockIdx.x * 128;
  f32x4 acc[4][4] = {};

  for (int k0 = 0; k0 < K; k0 += BK) {
    short8v areg[4], breg[4];
#pragma unroll
    for (int j = 0; j < 4; ++j) {
      int e = tid + j * 256;
      int r = e >> 3, cb = (e & 7) * 16;
      areg[j] = *(const short8v*)((const char*)A + ((size_t)(row0 + r) * K + k0) * 2 + cb);
      breg[j] = *(const short8v*)((const char*)Bt + ((size_t)(col0 + r) * K + k0) * 2 + cb);
    }
    __syncthreads();
#pragma unroll
    for (int j = 0; j < 4; ++j) {
      int e = tid + j * 256;
      int r = e >> 3, cb = (e & 7) * 16;
      int sw = cb ^ ((r & 7) << 4);
      *(short8v*)((char*)As + r * 128 + sw) = areg[j];
      *(short8v*)((char*)Bs + r * 128 + sw) = breg[j];
    }
    __syncthreads();
#pragma unroll
    for (int kk = 0; kk < 2; ++kk) {
      short8v af[4], bf[4];
#pragma unroll
      for (int m = 0; m < 4; ++m) {
        int r = wr * 64 + m * 16 + (lane & 15);
        int cb = kk * 64 + (lane >> 4) * 16;
        af[m] = *(const short8v*)((const char*)As + r * 128 + (cb ^ ((r & 7) << 4)));
      }
#pragma unroll
      for (int n = 0; n < 4; ++n) {
        int r = wc * 64 + n * 16 + (lane & 15);
        int cb = kk * 64 + (lane >> 4) * 16;
        bf[n] = *(const short8v*)((const char*)Bs + r * 128 + (cb ^ ((r & 7) << 4)));
      }
#pragma unroll
      for (int m = 0; m < 4; ++m)
#pragma unroll
        for (int n = 0; n < 4; ++n)
          acc[m][n] = __builtin_amdgcn_mfma_f32_16x16x32_bf16(af[m], bf[n], acc[m][n], 0, 0, 0);
    }
  }

#pragma unroll
  for (int m = 0; m < 4; ++m) {
    int rowb = row0 + wr * 64 + m * 16 + (lane >> 4) * 4;
#pragma unroll
    for (int r = 0; r < 4; ++r) {
      int rr = rowb + r;
      if (rr >= M) continue;
#pragma unroll
      for (int n = 0; n < 4; ++n) {
        int col = col0 + wc * 64 + n * 16 + (lane & 15);
        float v = acc[m][n][r] + bias[col];
        if (mode == 0) {
          ((float*)Cout)[(size_t)rr * N + col] = v;
        } else if (mode == 2) {
          ((float*)Cout)[(size_t)rr * N + col] = v + add[(size_t)rr * N + col];
        } else {
          if (col < 512) ((float*)Cout)[(size_t)rr * 512 + col] = v;
          else           ((float*)Cout2)[(size_t)rr * 256 + (col - 512)] = v;
        }
      }
    }
  }
}

// ------- Wv GEMM: 512 thr, tile 128x256 (full N) so A is staged ONCE. -------
__global__ __launch_bounds__(512) void gemm_wv_f32(
    const float* __restrict__ A, const u16* __restrict__ Bt,
    const float* __restrict__ bias, u8* __restrict__ Cout, int M) {
  constexpr int K = 256, BK = 64;
  __shared__ u16 As[128 * BK];   // 16 KB
  __shared__ u16 Bs[256 * BK];   // 32 KB
  const int tid = threadIdx.x;
  const int lane = tid & 63, w = tid >> 6;
  const int wr = w >> 2, wc = w & 3;
  const int row0 = blockIdx.x * 128;
  f32x4 acc[4][4] = {};

  for (int k0 = 0; k0 < K; k0 += BK) {
    short8v areg[2], breg[4];
#pragma unroll
    for (int j = 0; j < 2; ++j) {
      int e = tid + j * 512;
      int r = e >> 3, co = (e & 7) * 8;
      u16 tmp[8];
      if (row0 + r < M) {
        const float* src = A + (size_t)(row0 + r) * K + k0 + co;
        float4 f0 = *(const float4*)src;
        float4 f1 = *(const float4*)(src + 4);
        tmp[0] = f2bf(f0.x); tmp[1] = f2bf(f0.y); tmp[2] = f2bf(f0.z); tmp[3] = f2bf(f0.w);
        tmp[4] = f2bf(f1.x); tmp[5] = f2bf(f1.y); tmp[6] = f2bf(f1.z); tmp[7] = f2bf(f1.w);
      } else {
#pragma unroll
        for (int t = 0; t < 8; ++t) tmp[t] = 0;
      }
      areg[j] = *(short8v*)tmp;
    }
#pragma unroll
    for (int j = 0; j < 4; ++j) {
      int e = tid + j * 512;
      int r = e >> 3, cb = (e & 7) * 16;
      breg[j] = *(const short8v*)((const char*)Bt + ((size_t)r * K + k0) * 2 + cb);
    }
    __syncthreads();
#pragma unroll
    for (int j = 0; j < 2; ++j) {
      int e = tid + j * 512;
      int r = e >> 3, cb = (e & 7) * 16;
      *(short8v*)((char*)As + r * 128 + (cb ^ ((r & 7) << 4))) = areg[j];
    }
#pragma unroll
    for (int j = 0; j < 4; ++j) {
      int e = tid + j * 512;
      int r = e >> 3, cb = (e & 7) * 16;
      *(short8v*)((char*)Bs + r * 128 + (cb ^ ((r & 7) << 4))) = breg[j];
    }
    __syncthreads();
#pragma unroll
    for (int kk = 0; kk < 2; ++kk) {
      short8v af[4], bf[4];
#pragma unroll
      for (int m = 0; m < 4; ++m) {
        int r = wr * 64 + m * 16 + (lane & 15);
        int cb = kk * 64 + (lane >> 4) * 16;
        af[m] = *(const short8v*)((const char*)As + r * 128 + (cb ^ ((r & 7) << 4)));
      }
#pragma unroll
      for (int n = 0; n < 4; ++n) {
        int r = wc * 64 + n * 16 + (lane & 15);
        int cb = kk * 64 + (lane >> 4) * 16;
        bf[n] = *(const short8v*)((const char*)Bs + r * 128 + (cb ^ ((r & 7) << 4)));
      }
#pragma unroll
      for (int m = 0; m < 4; ++m)
#pragma unroll
        for (int n = 0; n < 4; ++n)
          acc[m][n] = __builtin_amdgcn_mfma_f32_16x16x32_bf16(af[m], bf[n], acc[m][n], 0, 0, 0);
    }
  }

#pragma unroll
  for (int m = 0; m < 4; ++m) {
    int rowb = row0 + wr * 64 + m * 16 + (lane >> 4) * 4;
#pragma unroll
    for (int r = 0; r < 4; ++r) {
      int rr = rowb + r;
      if (rr >= M) continue;
      int cam = rr / NV;
      int px = rr - cam * NV;
#pragma unroll
      for (int n = 0; n < 4; ++n) {
        int col = wc * 64 + n * 16 + (lane & 15);
        float v = acc[m][n][r] + bias[col];
        int h = col >> 5, d = col & 31;
        int pk = __builtin_amdgcn_cvt_pk_fp8_f32(v, v, 0, false);
        Cout[(((size_t)cam * HEADS + h) * NV + px) * 32 + d] = (u8)(pk & 0xff);
      }
    }
  }
}

// ---------------- softmax over 32 (per q,head), z-major layout ----------------
__global__ void softmax_kernel(float* __restrict__ att) {
  int r = blockIdx.x * blockDim.x + threadIdx.x;
  if (r >= NQ * HEADS) return;
  int q = r >> 3, h = r & 7;
  float* base = att + (size_t)q * 256 + h * 8;
  float v[32];
  float mx = -1e30f;
  int n = 0;
#pragma unroll
  for (int z = 0; z < 4; ++z)
#pragma unroll
    for (int l = 0; l < 4; ++l)
#pragma unroll
      for (int pi = 0; pi < 2; ++pi) {
        float x = base[z * 64 + l * 2 + pi];
        v[n++] = x;
        mx = fmaxf(mx, x);
      }
  float sm = 0.f;
#pragma unroll
  for (int i = 0; i < 32; ++i) { v[i] = expf(v[i] - mx); sm += v[i]; }
  float inv = 1.0f / sm;
  n = 0;
#pragma unroll
  for (int z = 0; z < 4; ++z)
#pragma unroll
    for (int l = 0; l < 4; ++l)
#pragma unroll
      for (int pi = 0; pi < 2; ++pi)
        base[z * 64 + l * 2 + pi] = v[n++] * inv;
}

// ---------------- deformable sampling: one wave per SORTED (cam,q,z) item ----------------
// NEW lane map: lane = h(3b)|l(2b)|pi(1b) — one point per lane, scalar math ONCE
// (was 4x duplicated across dim-group lanes + per-level loop). Each lane gathers
// 4 corners x 32 fp8 dims (2x dwordx4 each), accumulates 32 dims in 16 f32x2
// (packed fma), then 3-level shfl_xor reduce over the 8 point-lanes per head.
// Lane (l,pi)==0 writes the 64B bf16 row. launch_bounds(256,4): VGPR cap 128.
__global__ __launch_bounds__(256, 4) void sample_kernel(
    const u8* __restrict__ vproj, const float* __restrict__ offr,
    const float* __restrict__ attw, const float* __restrict__ ref,
    const u32* __restrict__ perm, const u32* __restrict__ total,
    u16* __restrict__ part2) {
  constexpr int Hs[4] = {92, 46, 23, 12};
  constexpr int Ws[4] = {160, 80, 40, 20};
  constexpr int LSI[4] = {0, 14720, 18400, 19320};
  const int idx = blockIdx.x * 4 + (threadIdx.x >> 6);
  if (idx >= (int)*total) return;
  const u32 item = perm[idx];
  const int c = item >> 16;
  const int z = (item >> 14) & 3;
  const int q = item & 0x3fff;
  const int lane = threadIdx.x & 63;
  const int h = lane >> 3;
  const int l = (lane >> 1) & 3;
  const int pi = lane & 1;

  const int W = Ws[l], H = Hs[l];
  const float* rc = ref + ((size_t)c * NQ + q) * 8 + z * 2;
  const float rx = rc[0], ry = rc[1];
  float2 o = *(const float2*)&offr[(size_t)q * 512 + z * 128 + h * 16 + l * 4 + pi * 2];
  float a = attw[(size_t)q * 256 + z * 64 + h * 8 + l * 2 + pi];
  const u8* vl = vproj + ((size_t)c * HEADS + h) * NV * 32 + (size_t)LSI[l] * 32;

  // per-point scalar math (once per lane)
  float x = rx * (float)W + o.x - 0.5f;
  float y = ry * (float)H + o.y - 0.5f;
  float x0f = floorf(x), y0f = floorf(y);
  float lx = x - x0f, ly = y - y0f;
  int x0 = (int)x0f, y0 = (int)y0f;
  float fx0 = (x0 >= 0 && x0 < W) ? 1.f : 0.f;
  float fx1 = (x0 >= -1 && x0 < W - 1) ? 1.f : 0.f;
  float fy0 = (y0 >= 0 && y0 < H) ? 1.f : 0.f;
  float fy1 = (y0 >= -1 && y0 < H - 1) ? 1.f : 0.f;
  int x0c = min(max(x0, 0), W - 1);
  int x1c = min(max(x0 + 1, 0), W - 1);
  int y0c = min(max(y0, 0), H - 1);
  int y1c = min(max(y0 + 1, 0), H - 1);
  float c00 = a * (1.f - lx) * (1.f - ly) * fx0 * fy0;
  float c01 = a * lx * (1.f - ly) * fx1 * fy0;
  float c10 = a * (1.f - lx) * ly * fx0 * fy1;
  float c11 = a * lx * ly * fx1 * fy1;

  // 4 corners x 32 fp8 dims
  const u8* p00 = vl + (size_t)(y0c * W + x0c) * 32;
  const u8* p01 = vl + (size_t)(y0c * W + x1c) * 32;
  const u8* p10 = vl + (size_t)(y1c * W + x0c) * 32;
  const u8* p11 = vl + (size_t)(y1c * W + x1c) * 32;
  uint4 A0 = *(const uint4*)p00, A1 = *(const uint4*)(p00 + 16);
  uint4 B0 = *(const uint4*)p01, B1 = *(const uint4*)(p01 + 16);
  uint4 C0 = *(const uint4*)p10, C1 = *(const uint4*)(p10 + 16);
  uint4 D0 = *(const uint4*)p11, D1 = *(const uint4*)(p11 + 16);

  f32x2 acc[16] = {};
  auto consume = [&](uint4 lo, uint4 hi, float wgt) {
    const u32 wds[8] = {lo.x, lo.y, lo.z, lo.w, hi.x, hi.y, hi.z, hi.w};
#pragma unroll
    for (int j = 0; j < 8; ++j) {
      f32x2 g0 = __builtin_amdgcn_cvt_pk_f32_fp8(wds[j], false);
      f32x2 g1 = __builtin_amdgcn_cvt_pk_f32_fp8(wds[j], true);
      acc[2 * j + 0] += g0 * wgt;
      acc[2 * j + 1] += g1 * wgt;
    }
  };
  consume(A0, A1, c00);
  consume(B0, B1, c01);
  consume(C0, C1, c10);
  consume(D0, D1, c11);

  // reduce over the 8 point-lanes of each head (lane bits 0-2)
#pragma unroll
  for (int mask = 1; mask <= 4; mask <<= 1) {
#pragma unroll
    for (int j = 0; j < 16; ++j) {
      f32x2 t;
      t.x = __shfl_xor(acc[j].x, mask);
      t.y = __shfl_xor(acc[j].y, mask);
      acc[j] += t;
    }
  }

  if ((lane & 7) == 0) {
    u16 o16[32];
#pragma unroll
    for (int j = 0; j < 16; ++j) {
      o16[2 * j + 0] = f2bf(acc[j].x);
      o16[2 * j + 1] = f2bf(acc[j].y);
    }
    u16* row = part2 + ((size_t)(z * CAMS + c) * NQ + q) * EMBED + h * 32;
#pragma unroll
    for (int j = 0; j < 4; ++j)
      __builtin_nontemporal_store(*(short8v*)&o16[j * 8], (short8v*)(row + j * 8));
  }
}

// ------- masked cam+z reduce (bf16 partials) + /count + bf16 pad: sbf(MQ_PAD,256) -------
__global__ void reduce_kernel(const u16* __restrict__ part2, const unsigned char* __restrict__ m,
                              const float* __restrict__ cinv, u16* __restrict__ sbf) {
  int i = blockIdx.x * blockDim.x + threadIdx.x;
  if (i >= MQ_PAD * 32) return;
  int row = i >> 5;
  int col = (i & 31) * 8;
  u16 o[8];
  if (row < NQ) {
    float s[8] = {};
    for (int c = 0; c < CAMS; ++c) {
      if (!m[c * NQ + row]) continue;
#pragma unroll
      for (int z = 0; z < 4; ++z) {
        const short8v* pp = (const short8v*)&part2[((size_t)(z * CAMS + c) * NQ + row) * EMBED + col];
        short8v v = __builtin_nontemporal_load(pp);
#pragma unroll
        for (int j = 0; j < 8; ++j) s[j] += bf2f((u16)v[j]);
      }
    }
    float sc = cinv[row];
#pragma unroll
    for (int j = 0; j < 8; ++j) o[j] = f2bf(s[j] * sc);
  } else {
#pragma unroll
    for (int j = 0; j < 8; ++j) o[j] = 0;
  }
  *(short8v*)&sbf[(size_t)row * 256 + col] = *(short8v*)o;
}

extern "C" void kernel_launch(void* const* d_in, const int* in_sizes, int n_in,
                              void* d_out, int out_size, void* d_ws, size_t ws_size,
                              hipStream_t stream) {
  const float* query     = (const float*)d_in[0];
  const float* query_pos = (const float*)d_in[1];
  const float* value     = (const float*)d_in[2];
  const float* refpts    = (const float*)d_in[3];
  const int*   bev       = (const int*)d_in[4];
  const float* Wv   = (const float*)d_in[7];
  const float* bv   = (const float*)d_in[8];
  const float* Woff = (const float*)d_in[9];
  const float* boff = (const float*)d_in[10];
  const float* Watt = (const float*)d_in[11];
  const float* batt = (const float*)d_in[12];
  const float* Wout = (const float*)d_in[13];
  const float* bout = (const float*)d_in[14];
  float* out = (float*)d_out;

  char* ws = (char*)d_ws;
  auto alloc = [&](size_t bytes) {
    char* p = ws;
    ws += (bytes + 255) & ~(size_t)255;
    return p;
  };
  u16*   qbf   = (u16*)alloc((size_t)MQ_PAD * 256 * 2);
  u16*   sbf   = (u16*)alloc((size_t)MQ_PAD * 256 * 2);
  u16*   WvT   = (u16*)alloc((size_t)256 * 256 * 2);
  u16*   WqT   = (u16*)alloc((size_t)768 * 256 * 2);   // permuted (z-major output cols)
  u16*   WoutT = (u16*)alloc((size_t)256 * 256 * 2);
  float* catb  = (float*)alloc((size_t)768 * 4);
  float* offr  = (float*)alloc((size_t)MQ_PAD * 512 * 4);
  float* attw  = (float*)alloc((size_t)MQ_PAD * 256 * 4);
  u8*    vproj = (u8*)alloc((size_t)CAMS * NV * EMBED);
  u16*   part2 = (u16*)alloc((size_t)4 * CAMS * NQ * EMBED * 2);
  float* cinv  = (float*)alloc((size_t)NQ * 4);
  unsigned char* msk = (unsigned char*)alloc((size_t)CAMS * NQ);
  u32*   hist  = (u32*)alloc((size_t)NBUCK * 4);
  u32*   cursor= (u32*)alloc((size_t)NBUCK * 4);
  u32*   total = (u32*)alloc(256);
  u32*   perm  = (u32*)alloc((size_t)MAXITEMS * 4);

  hipMemsetAsync(hist, 0, NBUCK * 4, stream);

  conv_bf16_kernel<<<(MQ_PAD * 32 + 255) / 256, 256, 0, stream>>>(query, query_pos, qbf, NQ, MQ_PAD);
  mask_kernel<<<(NQ + 255) / 256, 256, 0, stream>>>(bev, refpts, msk, cinv, hist);
  transpose_wq_kernel<<<(768 * 256 + 255) / 256, 256, 0, stream>>>(Woff, Watt, boff, batt, WqT, catb);
  transpose_w_kernel<<<256, 256, 0, stream>>>(Wv, WvT, 256);
  transpose_w_kernel<<<256, 256, 0, stream>>>(Wout, WoutT, 256);

  scan_kernel<<<1, NBUCK, 0, stream>>>(hist, cursor, total);
  scatter_kernel<<<(NQ + 255) / 256, 256, 0, stream>>>(refpts, msk, cursor, perm);

  dim3 gQ(768 / 128, MQ_PAD / 128);
  gemm_mfma<<<gQ, 256, 0, stream>>>(qbf, WqT, catb, nullptr, offr, attw, NQ, 768, 3);
  softmax_kernel<<<(NQ * HEADS + 255) / 256, 256, 0, stream>>>(attw);

  gemm_wv_f32<<<MV_PAD / 128, 512, 0, stream>>>(value, WvT, bv, vproj, CAMS * NV);

  sample_kernel<<<MAXITEMS / 4, 256, 0, stream>>>(vproj, offr, attw, refpts, perm, total, part2);

  reduce_kernel<<<(MQ_PAD * 32 + 255) / 256, 256, 0, stream>>>(part2, msk, cinv, sbf);
  dim3 gOut(256 / 128, MQ_PAD / 128);
  gemm_mfma<<<gOut, 256, 0, stream>>>(sbf, WoutT, bout, query, out, nullptr, NQ, 256, 2);
}

// Round 16
// 448.732 us; speedup vs baseline: 1.0648x; 1.0648x over previous
//
#include <hip/hip_runtime.h>
#include <hip/hip_bf16.h>

constexpr int NQ = 10000, NV = 19560, CAMS = 6, EMBED = 256, HEADS = 8,
              HEAD_DIM = 32, LEVELS = 4, POINTS = 8;
constexpr int MQ_PAD = 10112;          // 79 * 128
constexpr int MV_PAD = 117376;         // 917 * 128
constexpr int NBUCK = CAMS * 128;      // 16x8 tiles per cam
constexpr int MAXITEMS = CAMS * NQ * 4;

typedef unsigned int u32;
typedef unsigned short u16;
typedef unsigned char u8;
typedef __attribute__((ext_vector_type(8))) short short8v;
typedef __attribute__((ext_vector_type(4))) float f32x4;
typedef __attribute__((ext_vector_type(2))) float f32x2;

__device__ inline u16 f2bf(float f) {
  __hip_bfloat16 b = __float2bfloat16(f);
  return *(u16*)&b;
}
__device__ inline float bf2f(u16 v) { union { u32 i; float f; } x; x.i = (u32)v << 16; return x.f; }

// ---------------- fp32 -> bf16 row-padded convert (optional fused add) ----------------
__global__ void conv_bf16_kernel(const float* __restrict__ a, const float* __restrict__ b,
                                 u16* __restrict__ dst, int M, int Mpad) {
  int i = blockIdx.x * blockDim.x + threadIdx.x;
  if (i >= Mpad * 32) return;
  int row = i >> 5;
  int col = (i & 31) * 8;
  u16 o[8];
  if (row < M) {
    const float* pa = a + (size_t)row * 256 + col;
#pragma unroll
    for (int j = 0; j < 8; ++j) {
      float v = pa[j];
      if (b) v += b[(size_t)row * 256 + col + j];
      o[j] = f2bf(v);
    }
  } else {
#pragma unroll
    for (int j = 0; j < 8; ++j) o[j] = 0;
  }
  *(short8v*)&dst[(size_t)row * 256 + col] = *(short8v*)o;
}

// ---------------- plain weight transpose: src (K=256, N) -> dst (N, 256) bf16 ----------------
__global__ void transpose_w_kernel(const float* __restrict__ src, u16* __restrict__ dst, int N) {
  int g = blockIdx.x * blockDim.x + threadIdx.x;
  if (g >= N * 256) return;
  int n = g >> 8, k = g & 255;
  dst[(size_t)n * 256 + k] = f2bf(src[(size_t)k * N + n]);
}

// ------- permuted transpose for WqT (z-major output cols) + permuted catb -------
__device__ inline int orig_off_col(int j) {          // j in [0,512)
  int z = (j >> 7) & 3, h = (j >> 4) & 7, l = (j >> 2) & 3, pi = (j >> 1) & 1, xy = j & 1;
  return h * 64 + l * 16 + (z + 4 * pi) * 2 + xy;
}
__device__ inline int orig_att_col(int j) {          // j in [0,256)
  int z = (j >> 6) & 3, h = (j >> 3) & 7, l = (j >> 1) & 3, pi = j & 1;
  return h * 32 + l * 8 + (z + 4 * pi);
}
__global__ void transpose_wq_kernel(const float* __restrict__ Woff, const float* __restrict__ Watt,
                                    const float* __restrict__ boff, const float* __restrict__ batt,
                                    u16* __restrict__ WqT, float* __restrict__ catb) {
  int g = blockIdx.x * blockDim.x + threadIdx.x;
  if (g >= 768 * 256) return;
  int j = g >> 8, k = g & 255;
  float v;
  if (j < 512) v = Woff[(size_t)k * 512 + orig_off_col(j)];
  else         v = Watt[(size_t)k * 256 + orig_att_col(j - 512)];
  WqT[(size_t)j * 256 + k] = f2bf(v);
  if (k == 0) catb[j] = (j < 512) ? boff[orig_off_col(j)] : batt[orig_att_col(j - 512)];
}

// ---------------- bucket key ----------------
__device__ inline int buck_key(int c, float rx, float ry) {
  int tx = min(max((int)(rx * 16.f), 0), 15);
  int ty = min(max((int)(ry * 8.f), 0), 7);
  return c * 128 + ty * 16 + tx;
}

// ---------------- per-(cam,q) mask + 1/count + fused histogram ----------------
__global__ void mask_kernel(const int* __restrict__ bev, const float* __restrict__ ref,
                            unsigned char* __restrict__ m, float* __restrict__ cinv,
                            u32* __restrict__ hist) {
  int q = blockIdx.x * blockDim.x + threadIdx.x;
  if (q >= NQ) return;
  int cnt = 0;
  for (int c = 0; c < CAMS; ++c) {
    int any = 0;
    for (int z = 0; z < 4; ++z) any |= bev[((size_t)c * NQ + q) * 4 + z];
    m[c * NQ + q] = (unsigned char)(any != 0);
    cnt += (any != 0);
    if (any) {
      const float* rc = ref + ((size_t)c * NQ + q) * 8;
#pragma unroll
      for (int z = 0; z < 4; ++z)
        atomicAdd(&hist[buck_key(c, rc[z * 2], rc[z * 2 + 1])], 1u);
    }
  }
  cinv[q] = 1.0f / (float)(cnt > 0 ? cnt : 1);
}

// ---------------- exclusive scan over NBUCK buckets (one block) ----------------
__global__ void scan_kernel(const u32* __restrict__ hist, u32* __restrict__ cursor,
                            u32* __restrict__ total) {
  __shared__ u32 tmp[NBUCK];
  int t = threadIdx.x;
  u32 v = hist[t];
  tmp[t] = v;
  __syncthreads();
  for (int d = 1; d < NBUCK; d <<= 1) {
    u32 add = (t >= d) ? tmp[t - d] : 0;
    __syncthreads();
    tmp[t] += add;
    __syncthreads();
  }
  cursor[t] = tmp[t] - v;   // exclusive
  if (t == NBUCK - 1) *total = tmp[t];
}

// ---------------- scatter items into perm (sorted by bucket) ----------------
__global__ void scatter_kernel(const float* __restrict__ ref, const unsigned char* __restrict__ m,
                               u32* __restrict__ cursor, u32* __restrict__ perm) {
  int q = blockIdx.x * blockDim.x + threadIdx.x;
  if (q >= NQ) return;
  for (int c = 0; c < CAMS; ++c) {
    if (!m[c * NQ + q]) continue;
    const float* rc = ref + ((size_t)c * NQ + q) * 8;
#pragma unroll
    for (int z = 0; z < 4; ++z) {
      u32 pos = atomicAdd(&cursor[buck_key(c, rc[z * 2], rc[z * 2 + 1])], 1u);
      perm[pos] = ((u32)c << 16) | ((u32)z << 14) | (u32)q;
    }
  }
}

// ---------------- bf16 MFMA GEMM (128x128 tile, 256 thr) ----------------
// mode 0: fp32 out. mode 3: coalesced split.
__global__ __launch_bounds__(256) void gemm_mfma(
    const u16* __restrict__ A, const u16* __restrict__ Bt,
    const float* __restrict__ bias, const float* __restrict__ add,
    void* __restrict__ Cout, void* __restrict__ Cout2, int M, int N, int mode) {
  constexpr int K = 256, BK = 64;
  __shared__ u16 As[128 * BK];
  __shared__ u16 Bs[128 * BK];
  const int tid = threadIdx.x;
  const int lane = tid & 63, w = tid >> 6;
  const int wr = w >> 1, wc = w & 1;
  const int row0 = blockIdx.y * 128, col0 = blockIdx.x * 128;
  f32x4 acc[4][4] = {};

  for (int k0 = 0; k0 < K; k0 += BK) {
    short8v areg[4], breg[4];
#pragma unroll
    for (int j = 0; j < 4; ++j) {
      int e = tid + j * 256;
      int r = e >> 3, cb = (e & 7) * 16;
      areg[j] = *(const short8v*)((const char*)A + ((size_t)(row0 + r) * K + k0) * 2 + cb);
      breg[j] = *(const short8v*)((const char*)Bt + ((size_t)(col0 + r) * K + k0) * 2 + cb);
    }
    __syncthreads();
#pragma unroll
    for (int j = 0; j < 4; ++j) {
      int e = tid + j * 256;
      int r = e >> 3, cb = (e & 7) * 16;
      int sw = cb ^ ((r & 7) << 4);
      *(short8v*)((char*)As + r * 128 + sw) = areg[j];
      *(short8v*)((char*)Bs + r * 128 + sw) = breg[j];
    }
    __syncthreads();
#pragma unroll
    for (int kk = 0; kk < 2; ++kk) {
      short8v af[4], bf[4];
#pragma unroll
      for (int m = 0; m < 4; ++m) {
        int r = wr * 64 + m * 16 + (lane & 15);
        int cb = kk * 64 + (lane >> 4) * 16;
        af[m] = *(const short8v*)((const char*)As + r * 128 + (cb ^ ((r & 7) << 4)));
      }
#pragma unroll
      for (int n = 0; n < 4; ++n) {
        int r = wc * 64 + n * 16 + (lane & 15);
        int cb = kk * 64 + (lane >> 4) * 16;
        bf[n] = *(const short8v*)((const char*)Bs + r * 128 + (cb ^ ((r & 7) << 4)));
      }
#pragma unroll
      for (int m = 0; m < 4; ++m)
#pragma unroll
        for (int n = 0; n < 4; ++n)
          acc[m][n] = __builtin_amdgcn_mfma_f32_16x16x32_bf16(af[m], bf[n], acc[m][n], 0, 0, 0);
    }
  }

#pragma unroll
  for (int m = 0; m < 4; ++m) {
    int rowb = row0 + wr * 64 + m * 16 + (lane >> 4) * 4;
#pragma unroll
    for (int r = 0; r < 4; ++r) {
      int rr = rowb + r;
      if (rr >= M) continue;
#pragma unroll
      for (int n = 0; n < 4; ++n) {
        int col = col0 + wc * 64 + n * 16 + (lane & 15);
        float v = acc[m][n][r] + bias[col];
        if (mode == 0) {
          ((float*)Cout)[(size_t)rr * N + col] = v;
        } else {
          if (col < 512) ((float*)Cout)[(size_t)rr * 512 + col] = v;
          else           ((float*)Cout2)[(size_t)rr * 256 + (col - 512)] = v;
        }
      }
    }
  }
}

// ------- Wv GEMM: 512 thr, tile 128x256 (full N) so A is staged ONCE. -------
__global__ __launch_bounds__(512) void gemm_wv_f32(
    const float* __restrict__ A, const u16* __restrict__ Bt,
    const float* __restrict__ bias, u8* __restrict__ Cout, int M) {
  constexpr int K = 256, BK = 64;
  __shared__ u16 As[128 * BK];   // 16 KB
  __shared__ u16 Bs[256 * BK];   // 32 KB
  const int tid = threadIdx.x;
  const int lane = tid & 63, w = tid >> 6;
  const int wr = w >> 2, wc = w & 3;
  const int row0 = blockIdx.x * 128;
  f32x4 acc[4][4] = {};

  for (int k0 = 0; k0 < K; k0 += BK) {
    short8v areg[2], breg[4];
#pragma unroll
    for (int j = 0; j < 2; ++j) {
      int e = tid + j * 512;
      int r = e >> 3, co = (e & 7) * 8;
      u16 tmp[8];
      if (row0 + r < M) {
        const float* src = A + (size_t)(row0 + r) * K + k0 + co;
        float4 f0 = *(const float4*)src;
        float4 f1 = *(const float4*)(src + 4);
        tmp[0] = f2bf(f0.x); tmp[1] = f2bf(f0.y); tmp[2] = f2bf(f0.z); tmp[3] = f2bf(f0.w);
        tmp[4] = f2bf(f1.x); tmp[5] = f2bf(f1.y); tmp[6] = f2bf(f1.z); tmp[7] = f2bf(f1.w);
      } else {
#pragma unroll
        for (int t = 0; t < 8; ++t) tmp[t] = 0;
      }
      areg[j] = *(short8v*)tmp;
    }
#pragma unroll
    for (int j = 0; j < 4; ++j) {
      int e = tid + j * 512;
      int r = e >> 3, cb = (e & 7) * 16;
      breg[j] = *(const short8v*)((const char*)Bt + ((size_t)r * K + k0) * 2 + cb);
    }
    __syncthreads();
#pragma unroll
    for (int j = 0; j < 2; ++j) {
      int e = tid + j * 512;
      int r = e >> 3, cb = (e & 7) * 16;
      *(short8v*)((char*)As + r * 128 + (cb ^ ((r & 7) << 4))) = areg[j];
    }
#pragma unroll
    for (int j = 0; j < 4; ++j) {
      int e = tid + j * 512;
      int r = e >> 3, cb = (e & 7) * 16;
      *(short8v*)((char*)Bs + r * 128 + (cb ^ ((r & 7) << 4))) = breg[j];
    }
    __syncthreads();
#pragma unroll
    for (int kk = 0; kk < 2; ++kk) {
      short8v af[4], bf[4];
#pragma unroll
      for (int m = 0; m < 4; ++m) {
        int r = wr * 64 + m * 16 + (lane & 15);
        int cb = kk * 64 + (lane >> 4) * 16;
        af[m] = *(const short8v*)((const char*)As + r * 128 + (cb ^ ((r & 7) << 4)));
      }
#pragma unroll
      for (int n = 0; n < 4; ++n) {
        int r = wc * 64 + n * 16 + (lane & 15);
        int cb = kk * 64 + (lane >> 4) * 16;
        bf[n] = *(const short8v*)((const char*)Bs + r * 128 + (cb ^ ((r & 7) << 4)));
      }
#pragma unroll
      for (int m = 0; m < 4; ++m)
#pragma unroll
        for (int n = 0; n < 4; ++n)
          acc[m][n] = __builtin_amdgcn_mfma_f32_16x16x32_bf16(af[m], bf[n], acc[m][n], 0, 0, 0);
    }
  }

#pragma unroll
  for (int m = 0; m < 4; ++m) {
    int rowb = row0 + wr * 64 + m * 16 + (lane >> 4) * 4;
#pragma unroll
    for (int r = 0; r < 4; ++r) {
      int rr = rowb + r;
      if (rr >= M) continue;
      int cam = rr / NV;
      int px = rr - cam * NV;
#pragma unroll
      for (int n = 0; n < 4; ++n) {
        int col = wc * 64 + n * 16 + (lane & 15);
        float v = acc[m][n][r] + bias[col];
        int h = col >> 5, d = col & 31;
        int pk = __builtin_amdgcn_cvt_pk_fp8_f32(v, v, 0, false);
        Cout[(((size_t)cam * HEADS + h) * NV + px) * 32 + d] = (u8)(pk & 0xff);
      }
    }
  }
}

// ------- OUTPUT GEMM fused with masked 24-plane reduce: out = (Σ part2 * cinv) @ Wout^T + bout + query
// 512 thr, tile 128x256 (full N), A staged in-register from part2. -------
__global__ __launch_bounds__(512) void gemm_out_fused(
    const u16* __restrict__ part2, const unsigned char* __restrict__ msk,
    const float* __restrict__ cinv, const u16* __restrict__ Bt,
    const float* __restrict__ bias, const float* __restrict__ add,
    float* __restrict__ Cout) {
  constexpr int K = 256, BK = 64, M = NQ;
  __shared__ u16 As[128 * BK];   // 16 KB
  __shared__ u16 Bs[256 * BK];   // 32 KB
  const int tid = threadIdx.x;
  const int lane = tid & 63, w = tid >> 6;
  const int wr = w >> 2, wc = w & 3;
  const int row0 = blockIdx.x * 128;
  f32x4 acc[4][4] = {};

  for (int k0 = 0; k0 < K; k0 += BK) {
    short8v areg[2], breg[4];
#pragma unroll
    for (int j = 0; j < 2; ++j) {
      int e = tid + j * 512;
      int r = e >> 3, co = (e & 7) * 8;
      int row = row0 + r;
      u16 tmp[8];
      if (row < M) {
        float s[8] = {};
        for (int c = 0; c < CAMS; ++c) {
          if (!msk[c * NQ + row]) continue;
#pragma unroll
          for (int z = 0; z < 4; ++z) {
            short8v v = *(const short8v*)&part2[((size_t)(z * CAMS + c) * NQ + row) * EMBED + k0 + co];
#pragma unroll
            for (int t = 0; t < 8; ++t) s[t] += bf2f((u16)v[t]);
          }
        }
        float sc = cinv[row];
#pragma unroll
        for (int t = 0; t < 8; ++t) tmp[t] = f2bf(s[t] * sc);
      } else {
#pragma unroll
        for (int t = 0; t < 8; ++t) tmp[t] = 0;
      }
      areg[j] = *(short8v*)tmp;
    }
#pragma unroll
    for (int j = 0; j < 4; ++j) {
      int e = tid + j * 512;
      int r = e >> 3, cb = (e & 7) * 16;
      breg[j] = *(const short8v*)((const char*)Bt + ((size_t)r * K + k0) * 2 + cb);
    }
    __syncthreads();
#pragma unroll
    for (int j = 0; j < 2; ++j) {
      int e = tid + j * 512;
      int r = e >> 3, cb = (e & 7) * 16;
      *(short8v*)((char*)As + r * 128 + (cb ^ ((r & 7) << 4))) = areg[j];
    }
#pragma unroll
    for (int j = 0; j < 4; ++j) {
      int e = tid + j * 512;
      int r = e >> 3, cb = (e & 7) * 16;
      *(short8v*)((char*)Bs + r * 128 + (cb ^ ((r & 7) << 4))) = breg[j];
    }
    __syncthreads();
#pragma unroll
    for (int kk = 0; kk < 2; ++kk) {
      short8v af[4], bf[4];
#pragma unroll
      for (int m = 0; m < 4; ++m) {
        int r = wr * 64 + m * 16 + (lane & 15);
        int cb = kk * 64 + (lane >> 4) * 16;
        af[m] = *(const short8v*)((const char*)As + r * 128 + (cb ^ ((r & 7) << 4)));
      }
#pragma unroll
      for (int n = 0; n < 4; ++n) {
        int r = wc * 64 + n * 16 + (lane & 15);
        int cb = kk * 64 + (lane >> 4) * 16;
        bf[n] = *(const short8v*)((const char*)Bs + r * 128 + (cb ^ ((r & 7) << 4)));
      }
#pragma unroll
      for (int m = 0; m < 4; ++m)
#pragma unroll
        for (int n = 0; n < 4; ++n)
          acc[m][n] = __builtin_amdgcn_mfma_f32_16x16x32_bf16(af[m], bf[n], acc[m][n], 0, 0, 0);
    }
  }

#pragma unroll
  for (int m = 0; m < 4; ++m) {
    int rowb = row0 + wr * 64 + m * 16 + (lane >> 4) * 4;
#pragma unroll
    for (int r = 0; r < 4; ++r) {
      int rr = rowb + r;
      if (rr >= M) continue;
#pragma unroll
      for (int n = 0; n < 4; ++n) {
        int col = wc * 64 + n * 16 + (lane & 15);
        Cout[(size_t)rr * 256 + col] = acc[m][n][r] + bias[col] + add[(size_t)rr * 256 + col];
      }
    }
  }
}

// ---------------- softmax over 32 (per q,head), z-major layout ----------------
__global__ void softmax_kernel(float* __restrict__ att) {
  int r = blockIdx.x * blockDim.x + threadIdx.x;
  if (r >= NQ * HEADS) return;
  int q = r >> 3, h = r & 7;
  float* base = att + (size_t)q * 256 + h * 8;
  float v[32];
  float mx = -1e30f;
  int n = 0;
#pragma unroll
  for (int z = 0; z < 4; ++z)
#pragma unroll
    for (int l = 0; l < 4; ++l)
#pragma unroll
      for (int pi = 0; pi < 2; ++pi) {
        float x = base[z * 64 + l * 2 + pi];
        v[n++] = x;
        mx = fmaxf(mx, x);
      }
  float sm = 0.f;
#pragma unroll
  for (int i = 0; i < 32; ++i) { v[i] = expf(v[i] - mx); sm += v[i]; }
  float inv = 1.0f / sm;
  n = 0;
#pragma unroll
  for (int z = 0; z < 4; ++z)
#pragma unroll
    for (int l = 0; l < 4; ++l)
#pragma unroll
      for (int pi = 0; pi < 2; ++pi)
        base[z * 64 + l * 2 + pi] = v[n++] * inv;
}

// ---------------- deformable sampling: one wave per SORTED (cam,q,z) item ----------------
// R14 structure (lane = h|pp|dl, f32x2 pk-fma) with FULL level unroll so W/H/LSI are
// compile-time constants (unroll-2 left runtime-l select chains on every use).
__global__ __launch_bounds__(256, 8) void sample_kernel(
    const u8* __restrict__ vproj, const float* __restrict__ offr,
    const float* __restrict__ attw, const float* __restrict__ ref,
    const u32* __restrict__ perm, const u32* __restrict__ total,
    u16* __restrict__ part2) {
  constexpr int Hs[4] = {92, 46, 23, 12};
  constexpr int Ws[4] = {160, 80, 40, 20};
  constexpr int LSI[4] = {0, 14720, 18400, 19320};
  const int idx = blockIdx.x * 4 + (threadIdx.x >> 6);
  if (idx >= (int)*total) return;
  const u32 item = perm[idx];
  const int c = item >> 16;
  const int z = (item >> 14) & 3;
  const int q = item & 0x3fff;
  const int lane = threadIdx.x & 63;
  const int h = lane >> 3;
  const int pp = (lane >> 2) & 1;
  const int d0 = (lane & 3) * 8;

  const float* rc = ref + ((size_t)c * NQ + q) * 8 + z * 2;
  const float rx = rc[0], ry = rc[1];
  const float* offq = offr + (size_t)q * 512 + z * 128 + h * 16;
  const float* attq = attw + (size_t)q * 256 + z * 64 + h * 8;
  const u8* vch = vproj + ((size_t)c * HEADS + h) * NV * 32 + d0;

  f32x2 acc2[4] = {};
#pragma unroll
  for (int l = 0; l < LEVELS; ++l) {
    const int W = Ws[l], H = Hs[l];
    const u8* vl = vch + (size_t)LSI[l] * 32;
    float2 o = *(const float2*)&offq[l * 4 + pp * 2];
    float a = attq[l * 2 + pp];
    float x = rx * (float)W + o.x - 0.5f;
    float y = ry * (float)H + o.y - 0.5f;
    float x0f = floorf(x), y0f = floorf(y);
    float lx = x - x0f, ly = y - y0f;
    int x0 = (int)x0f, y0 = (int)y0f;
    float fx0 = (x0 >= 0 && x0 < W) ? 1.f : 0.f;
    float fx1 = (x0 >= -1 && x0 < W - 1) ? 1.f : 0.f;
    float fy0 = (y0 >= 0 && y0 < H) ? 1.f : 0.f;
    float fy1 = (y0 >= -1 && y0 < H - 1) ? 1.f : 0.f;
    int x0c = min(max(x0, 0), W - 1);
    int x1c = min(max(x0 + 1, 0), W - 1);
    int y0c = min(max(y0, 0), H - 1);
    int y1c = min(max(y0 + 1, 0), H - 1);
    uint2 v00 = *(const uint2*)(vl + (size_t)(y0c * W + x0c) * 32);
    uint2 v01 = *(const uint2*)(vl + (size_t)(y0c * W + x1c) * 32);
    uint2 v10 = *(const uint2*)(vl + (size_t)(y1c * W + x0c) * 32);
    uint2 v11 = *(const uint2*)(vl + (size_t)(y1c * W + x1c) * 32);
    float c00 = a * (1.f - lx) * (1.f - ly) * fx0 * fy0;
    float c01 = a * lx * (1.f - ly) * fx1 * fy0;
    float c10 = a * (1.f - lx) * ly * fx0 * fy1;
    float c11 = a * lx * ly * fx1 * fy1;
#pragma unroll
    for (int half = 0; half < 2; ++half) {
      u32 w00 = half ? v00.y : v00.x, w01 = half ? v01.y : v01.x;
      u32 w10 = half ? v10.y : v10.x, w11 = half ? v11.y : v11.x;
      f32x2 gA0 = __builtin_amdgcn_cvt_pk_f32_fp8(w00, false);
      f32x2 gA1 = __builtin_amdgcn_cvt_pk_f32_fp8(w00, true);
      f32x2 gB0 = __builtin_amdgcn_cvt_pk_f32_fp8(w01, false);
      f32x2 gB1 = __builtin_amdgcn_cvt_pk_f32_fp8(w01, true);
      f32x2 gC0 = __builtin_amdgcn_cvt_pk_f32_fp8(w10, false);
      f32x2 gC1 = __builtin_amdgcn_cvt_pk_f32_fp8(w10, true);
      f32x2 gD0 = __builtin_amdgcn_cvt_pk_f32_fp8(w11, false);
      f32x2 gD1 = __builtin_amdgcn_cvt_pk_f32_fp8(w11, true);
      int b = half * 2;
      acc2[b + 0] += gA0 * c00 + gB0 * c01 + gC0 * c10 + gD0 * c11;
      acc2[b + 1] += gA1 * c00 + gB1 * c01 + gC1 * c10 + gD1 * c11;
    }
  }
  float accs[8] = {acc2[0].x, acc2[0].y, acc2[1].x, acc2[1].y,
                   acc2[2].x, acc2[2].y, acc2[3].x, acc2[3].y};
#pragma unroll
  for (int d = 0; d < 8; ++d) accs[d] += __shfl_xor(accs[d], 4);
  if (pp == 0) {
    u16 o[8];
#pragma unroll
    for (int d = 0; d < 8; ++d) o[d] = f2bf(accs[d]);
    short8v* sp = (short8v*)&part2[((size_t)(z * CAMS + c) * NQ + q) * EMBED + h * 32 + d0];
    __builtin_nontemporal_store(*(short8v*)o, sp);
  }
}

extern "C" void kernel_launch(void* const* d_in, const int* in_sizes, int n_in,
                              void* d_out, int out_size, void* d_ws, size_t ws_size,
                              hipStream_t stream) {
  const float* query     = (const float*)d_in[0];
  const float* query_pos = (const float*)d_in[1];
  const float* value     = (const float*)d_in[2];
  const float* refpts    = (const float*)d_in[3];
  const int*   bev       = (const int*)d_in[4];
  const float* Wv   = (const float*)d_in[7];
  const float* bv   = (const float*)d_in[8];
  const float* Woff = (const float*)d_in[9];
  const float* boff = (const float*)d_in[10];
  const float* Watt = (const float*)d_in[11];
  const float* batt = (const float*)d_in[12];
  const float* Wout = (const float*)d_in[13];
  const float* bout = (const float*)d_in[14];
  float* out = (float*)d_out;

  char* ws = (char*)d_ws;
  auto alloc = [&](size_t bytes) {
    char* p = ws;
    ws += (bytes + 255) & ~(size_t)255;
    return p;
  };
  u16*   qbf   = (u16*)alloc((size_t)MQ_PAD * 256 * 2);
  u16*   WvT   = (u16*)alloc((size_t)256 * 256 * 2);
  u16*   WqT   = (u16*)alloc((size_t)768 * 256 * 2);   // permuted (z-major output cols)
  u16*   WoutT = (u16*)alloc((size_t)256 * 256 * 2);
  float* catb  = (float*)alloc((size_t)768 * 4);
  float* offr  = (float*)alloc((size_t)MQ_PAD * 512 * 4);
  float* attw  = (float*)alloc((size_t)MQ_PAD * 256 * 4);
  u8*    vproj = (u8*)alloc((size_t)CAMS * NV * EMBED);
  u16*   part2 = (u16*)alloc((size_t)4 * CAMS * NQ * EMBED * 2);
  float* cinv  = (float*)alloc((size_t)NQ * 4);
  unsigned char* msk = (unsigned char*)alloc((size_t)CAMS * NQ);
  u32*   hist  = (u32*)alloc((size_t)NBUCK * 4);
  u32*   cursor= (u32*)alloc((size_t)NBUCK * 4);
  u32*   total = (u32*)alloc(256);
  u32*   perm  = (u32*)alloc((size_t)MAXITEMS * 4);

  hipMemsetAsync(hist, 0, NBUCK * 4, stream);

  conv_bf16_kernel<<<(MQ_PAD * 32 + 255) / 256, 256, 0, stream>>>(query, query_pos, qbf, NQ, MQ_PAD);
  mask_kernel<<<(NQ + 255) / 256, 256, 0, stream>>>(bev, refpts, msk, cinv, hist);
  transpose_wq_kernel<<<(768 * 256 + 255) / 256, 256, 0, stream>>>(Woff, Watt, boff, batt, WqT, catb);
  transpose_w_kernel<<<256, 256, 0, stream>>>(Wv, WvT, 256);
  transpose_w_kernel<<<256, 256, 0, stream>>>(Wout, WoutT, 256);

  scan_kernel<<<1, NBUCK, 0, stream>>>(hist, cursor, total);
  scatter_kernel<<<(NQ + 255) / 256, 256, 0, stream>>>(refpts, msk, cursor, perm);

  dim3 gQ(768 / 128, MQ_PAD / 128);
  gemm_mfma<<<gQ, 256, 0, stream>>>(qbf, WqT, catb, nullptr, offr, attw, NQ, 768, 3);
  softmax_kernel<<<(NQ * HEADS + 255) / 256, 256, 0, stream>>>(attw);

  gemm_wv_f32<<<MV_PAD / 128, 512, 0, stream>>>(value, WvT, bv, vproj, CAMS * NV);

  sample_kernel<<<MAXITEMS / 4, 256, 0, stream>>>(vproj, offr, attw, refpts, perm, total, part2);

  gemm_out_fused<<<MQ_PAD / 128, 512, 0, stream>>>(part2, msk, cinv, WoutT, bout, query, out);
}

// Round 17
// 428.575 us; speedup vs baseline: 1.1149x; 1.0470x over previous
//
#include <hip/hip_runtime.h>
#include <hip/hip_bf16.h>

constexpr int NQ = 10000, NV = 19560, CAMS = 6, EMBED = 256, HEADS = 8,
              HEAD_DIM = 32, LEVELS = 4, POINTS = 8;
constexpr int MQ_PAD = 10112;          // 79 * 128
constexpr int MV_PAD = 117376;         // 917 * 128
constexpr int NBUCK = CAMS * 128;      // 16x8 tiles per cam
constexpr int MAXITEMS = CAMS * NQ * 4;

typedef unsigned int u32;
typedef unsigned short u16;
typedef unsigned char u8;
typedef __attribute__((ext_vector_type(8))) short short8v;
typedef __attribute__((ext_vector_type(4))) float f32x4;
typedef __attribute__((ext_vector_type(2))) float f32x2;

__device__ inline u16 f2bf(float f) {
  __hip_bfloat16 b = __float2bfloat16(f);
  return *(u16*)&b;
}
__device__ inline float bf2f(u16 v) { union { u32 i; float f; } x; x.i = (u32)v << 16; return x.f; }

// ---------------- fp32 -> bf16 row-padded convert (optional fused add) ----------------
__global__ void conv_bf16_kernel(const float* __restrict__ a, const float* __restrict__ b,
                                 u16* __restrict__ dst, int M, int Mpad) {
  int i = blockIdx.x * blockDim.x + threadIdx.x;
  if (i >= Mpad * 32) return;
  int row = i >> 5;
  int col = (i & 31) * 8;
  u16 o[8];
  if (row < M) {
    const float* pa = a + (size_t)row * 256 + col;
#pragma unroll
    for (int j = 0; j < 8; ++j) {
      float v = pa[j];
      if (b) v += b[(size_t)row * 256 + col + j];
      o[j] = f2bf(v);
    }
  } else {
#pragma unroll
    for (int j = 0; j < 8; ++j) o[j] = 0;
  }
  *(short8v*)&dst[(size_t)row * 256 + col] = *(short8v*)o;
}

// ---------------- plain weight transpose: src (K=256, N) -> dst (N, 256) bf16 ----------------
__global__ void transpose_w_kernel(const float* __restrict__ src, u16* __restrict__ dst, int N) {
  int g = blockIdx.x * blockDim.x + threadIdx.x;
  if (g >= N * 256) return;
  int n = g >> 8, k = g & 255;
  dst[(size_t)n * 256 + k] = f2bf(src[(size_t)k * N + n]);
}

// ------- permuted transpose for WqT (z-major output cols) + permuted catb -------
__device__ inline int orig_off_col(int j) {          // j in [0,512)
  int z = (j >> 7) & 3, h = (j >> 4) & 7, l = (j >> 2) & 3, pi = (j >> 1) & 1, xy = j & 1;
  return h * 64 + l * 16 + (z + 4 * pi) * 2 + xy;
}
__device__ inline int orig_att_col(int j) {          // j in [0,256)
  int z = (j >> 6) & 3, h = (j >> 3) & 7, l = (j >> 1) & 3, pi = j & 1;
  return h * 32 + l * 8 + (z + 4 * pi);
}
__global__ void transpose_wq_kernel(const float* __restrict__ Woff, const float* __restrict__ Watt,
                                    const float* __restrict__ boff, const float* __restrict__ batt,
                                    u16* __restrict__ WqT, float* __restrict__ catb) {
  int g = blockIdx.x * blockDim.x + threadIdx.x;
  if (g >= 768 * 256) return;
  int j = g >> 8, k = g & 255;
  float v;
  if (j < 512) v = Woff[(size_t)k * 512 + orig_off_col(j)];
  else         v = Watt[(size_t)k * 256 + orig_att_col(j - 512)];
  WqT[(size_t)j * 256 + k] = f2bf(v);
  if (k == 0) catb[j] = (j < 512) ? boff[orig_off_col(j)] : batt[orig_att_col(j - 512)];
}

// ---------------- bucket key ----------------
__device__ inline int buck_key(int c, float rx, float ry) {
  int tx = min(max((int)(rx * 16.f), 0), 15);
  int ty = min(max((int)(ry * 8.f), 0), 7);
  return c * 128 + ty * 16 + tx;
}

// ---------------- per-(cam,q) mask + 1/count + fused histogram ----------------
__global__ void mask_kernel(const int* __restrict__ bev, const float* __restrict__ ref,
                            unsigned char* __restrict__ m, float* __restrict__ cinv,
                            u32* __restrict__ hist) {
  int q = blockIdx.x * blockDim.x + threadIdx.x;
  if (q >= NQ) return;
  int cnt = 0;
  for (int c = 0; c < CAMS; ++c) {
    int any = 0;
    for (int z = 0; z < 4; ++z) any |= bev[((size_t)c * NQ + q) * 4 + z];
    m[c * NQ + q] = (unsigned char)(any != 0);
    cnt += (any != 0);
    if (any) {
      const float* rc = ref + ((size_t)c * NQ + q) * 8;
#pragma unroll
      for (int z = 0; z < 4; ++z)
        atomicAdd(&hist[buck_key(c, rc[z * 2], rc[z * 2 + 1])], 1u);
    }
  }
  cinv[q] = 1.0f / (float)(cnt > 0 ? cnt : 1);
}

// ---------------- exclusive scan over NBUCK buckets (one block) ----------------
__global__ void scan_kernel(const u32* __restrict__ hist, u32* __restrict__ cursor,
                            u32* __restrict__ total) {
  __shared__ u32 tmp[NBUCK];
  int t = threadIdx.x;
  u32 v = hist[t];
  tmp[t] = v;
  __syncthreads();
  for (int d = 1; d < NBUCK; d <<= 1) {
    u32 add = (t >= d) ? tmp[t - d] : 0;
    __syncthreads();
    tmp[t] += add;
    __syncthreads();
  }
  cursor[t] = tmp[t] - v;   // exclusive
  if (t == NBUCK - 1) *total = tmp[t];
}

// ---------------- scatter items into perm (sorted by bucket) ----------------
__global__ void scatter_kernel(const float* __restrict__ ref, const unsigned char* __restrict__ m,
                               u32* __restrict__ cursor, u32* __restrict__ perm) {
  int q = blockIdx.x * blockDim.x + threadIdx.x;
  if (q >= NQ) return;
  for (int c = 0; c < CAMS; ++c) {
    if (!m[c * NQ + q]) continue;
    const float* rc = ref + ((size_t)c * NQ + q) * 8;
#pragma unroll
    for (int z = 0; z < 4; ++z) {
      u32 pos = atomicAdd(&cursor[buck_key(c, rc[z * 2], rc[z * 2 + 1])], 1u);
      perm[pos] = ((u32)c << 16) | ((u32)z << 14) | (u32)q;
    }
  }
}

// ---------------- bf16 MFMA GEMM (128x128 tile, 256 thr) ----------------
// mode 0: fp32 out. mode 2: fp32 out + add. mode 3: coalesced split.
__global__ __launch_bounds__(256) void gemm_mfma(
    const u16* __restrict__ A, const u16* __restrict__ Bt,
    const float* __restrict__ bias, const float* __restrict__ add,
    void* __restrict__ Cout, void* __restrict__ Cout2, int M, int N, int mode) {
  constexpr int K = 256, BK = 64;
  __shared__ u16 As[128 * BK];
  __shared__ u16 Bs[128 * BK];
  const int tid = threadIdx.x;
  const int lane = tid & 63, w = tid >> 6;
  const int wr = w >> 1, wc = w & 1;
  const int row0 = blockIdx.y * 128, col0 = blockIdx.x * 128;
  f32x4 acc[4][4] = {};

  for (int k0 = 0; k0 < K; k0 += BK) {
    short8v areg[4], breg[4];
#pragma unroll
    for (int j = 0; j < 4; ++j) {
      int e = tid + j * 256;
      int r = e >> 3, cb = (e & 7) * 16;
      areg[j] = *(const short8v*)((const char*)A + ((size_t)(row0 + r) * K + k0) * 2 + cb);
      breg[j] = *(const short8v*)((const char*)Bt + ((size_t)(col0 + r) * K + k0) * 2 + cb);
    }
    __syncthreads();
#pragma unroll
    for (int j = 0; j < 4; ++j) {
      int e = tid + j * 256;
      int r = e >> 3, cb = (e & 7) * 16;
      int sw = cb ^ ((r & 7) << 4);
      *(short8v*)((char*)As + r * 128 + sw) = areg[j];
      *(short8v*)((char*)Bs + r * 128 + sw) = breg[j];
    }
    __syncthreads();
#pragma unroll
    for (int kk = 0; kk < 2; ++kk) {
      short8v af[4], bf[4];
#pragma unroll
      for (int m = 0; m < 4; ++m) {
        int r = wr * 64 + m * 16 + (lane & 15);
        int cb = kk * 64 + (lane >> 4) * 16;
        af[m] = *(const short8v*)((const char*)As + r * 128 + (cb ^ ((r & 7) << 4)));
      }
#pragma unroll
      for (int n = 0; n < 4; ++n) {
        int r = wc * 64 + n * 16 + (lane & 15);
        int cb = kk * 64 + (lane >> 4) * 16;
        bf[n] = *(const short8v*)((const char*)Bs + r * 128 + (cb ^ ((r & 7) << 4)));
      }
#pragma unroll
      for (int m = 0; m < 4; ++m)
#pragma unroll
        for (int n = 0; n < 4; ++n)
          acc[m][n] = __builtin_amdgcn_mfma_f32_16x16x32_bf16(af[m], bf[n], acc[m][n], 0, 0, 0);
    }
  }

#pragma unroll
  for (int m = 0; m < 4; ++m) {
    int rowb = row0 + wr * 64 + m * 16 + (lane >> 4) * 4;
#pragma unroll
    for (int r = 0; r < 4; ++r) {
      int rr = rowb + r;
      if (rr >= M) continue;
#pragma unroll
      for (int n = 0; n < 4; ++n) {
        int col = col0 + wc * 64 + n * 16 + (lane & 15);
        float v = acc[m][n][r] + bias[col];
        if (mode == 0) {
          ((float*)Cout)[(size_t)rr * N + col] = v;
        } else if (mode == 2) {
          ((float*)Cout)[(size_t)rr * N + col] = v + add[(size_t)rr * N + col];
        } else {
          if (col < 512) ((float*)Cout)[(size_t)rr * 512 + col] = v;
          else           ((float*)Cout2)[(size_t)rr * 256 + (col - 512)] = v;
        }
      }
    }
  }
}

// ------- Wv GEMM: 512 thr, tile 128x256 (full N) so A is staged ONCE. -------
__global__ __launch_bounds__(512) void gemm_wv_f32(
    const float* __restrict__ A, const u16* __restrict__ Bt,
    const float* __restrict__ bias, u8* __restrict__ Cout, int M) {
  constexpr int K = 256, BK = 64;
  __shared__ u16 As[128 * BK];   // 16 KB
  __shared__ u16 Bs[256 * BK];   // 32 KB
  const int tid = threadIdx.x;
  const int lane = tid & 63, w = tid >> 6;
  const int wr = w >> 2, wc = w & 3;
  const int row0 = blockIdx.x * 128;
  f32x4 acc[4][4] = {};

  for (int k0 = 0; k0 < K; k0 += BK) {
    short8v areg[2], breg[4];
#pragma unroll
    for (int j = 0; j < 2; ++j) {
      int e = tid + j * 512;
      int r = e >> 3, co = (e & 7) * 8;
      u16 tmp[8];
      if (row0 + r < M) {
        const float* src = A + (size_t)(row0 + r) * K + k0 + co;
        float4 f0 = *(const float4*)src;
        float4 f1 = *(const float4*)(src + 4);
        tmp[0] = f2bf(f0.x); tmp[1] = f2bf(f0.y); tmp[2] = f2bf(f0.z); tmp[3] = f2bf(f0.w);
        tmp[4] = f2bf(f1.x); tmp[5] = f2bf(f1.y); tmp[6] = f2bf(f1.z); tmp[7] = f2bf(f1.w);
      } else {
#pragma unroll
        for (int t = 0; t < 8; ++t) tmp[t] = 0;
      }
      areg[j] = *(short8v*)tmp;
    }
#pragma unroll
    for (int j = 0; j < 4; ++j) {
      int e = tid + j * 512;
      int r = e >> 3, cb = (e & 7) * 16;
      breg[j] = *(const short8v*)((const char*)Bt + ((size_t)r * K + k0) * 2 + cb);
    }
    __syncthreads();
#pragma unroll
    for (int j = 0; j < 2; ++j) {
      int e = tid + j * 512;
      int r = e >> 3, cb = (e & 7) * 16;
      *(short8v*)((char*)As + r * 128 + (cb ^ ((r & 7) << 4))) = areg[j];
    }
#pragma unroll
    for (int j = 0; j < 4; ++j) {
      int e = tid + j * 512;
      int r = e >> 3, cb = (e & 7) * 16;
      *(short8v*)((char*)Bs + r * 128 + (cb ^ ((r & 7) << 4))) = breg[j];
    }
    __syncthreads();
#pragma unroll
    for (int kk = 0; kk < 2; ++kk) {
      short8v af[4], bf[4];
#pragma unroll
      for (int m = 0; m < 4; ++m) {
        int r = wr * 64 + m * 16 + (lane & 15);
        int cb = kk * 64 + (lane >> 4) * 16;
        af[m] = *(const short8v*)((const char*)As + r * 128 + (cb ^ ((r & 7) << 4)));
      }
#pragma unroll
      for (int n = 0; n < 4; ++n) {
        int r = wc * 64 + n * 16 + (lane & 15);
        int cb = kk * 64 + (lane >> 4) * 16;
        bf[n] = *(const short8v*)((const char*)Bs + r * 128 + (cb ^ ((r & 7) << 4)));
      }
#pragma unroll
      for (int m = 0; m < 4; ++m)
#pragma unroll
        for (int n = 0; n < 4; ++n)
          acc[m][n] = __builtin_amdgcn_mfma_f32_16x16x32_bf16(af[m], bf[n], acc[m][n], 0, 0, 0);
    }
  }

#pragma unroll
  for (int m = 0; m < 4; ++m) {
    int rowb = row0 + wr * 64 + m * 16 + (lane >> 4) * 4;
#pragma unroll
    for (int r = 0; r < 4; ++r) {
      int rr = rowb + r;
      if (rr >= M) continue;
      int cam = rr / NV;
      int px = rr - cam * NV;
#pragma unroll
      for (int n = 0; n < 4; ++n) {
        int col = wc * 64 + n * 16 + (lane & 15);
        float v = acc[m][n][r] + bias[col];
        int h = col >> 5, d = col & 31;
        int pk = __builtin_amdgcn_cvt_pk_fp8_f32(v, v, 0, false);
        Cout[(((size_t)cam * HEADS + h) * NV + px) * 32 + d] = (u8)(pk & 0xff);
      }
    }
  }
}

// ---------------- softmax over 32 (per q,head), z-major layout ----------------
__global__ void softmax_kernel(float* __restrict__ att) {
  int r = blockIdx.x * blockDim.x + threadIdx.x;
  if (r >= NQ * HEADS) return;
  int q = r >> 3, h = r & 7;
  float* base = att + (size_t)q * 256 + h * 8;
  float v[32];
  float mx = -1e30f;
  int n = 0;
#pragma unroll
  for (int z = 0; z < 4; ++z)
#pragma unroll
    for (int l = 0; l < 4; ++l)
#pragma unroll
      for (int pi = 0; pi < 2; ++pi) {
        float x = base[z * 64 + l * 2 + pi];
        v[n++] = x;
        mx = fmaxf(mx, x);
      }
  float sm = 0.f;
#pragma unroll
  for (int i = 0; i < 32; ++i) { v[i] = expf(v[i] - mx); sm += v[i]; }
  float inv = 1.0f / sm;
  n = 0;
#pragma unroll
  for (int z = 0; z < 4; ++z)
#pragma unroll
    for (int l = 0; l < 4; ++l)
#pragma unroll
      for (int pi = 0; pi < 2; ++pi)
        base[z * 64 + l * 2 + pi] = v[n++] * inv;
}

// ---------------- deformable sampling: one wave per SORTED (cam,q,z) item ----------------
// R16 structure: lane = h|pp|dl, f32x2 pk-fma, FULL level unroll (W/H/LSI compile-time).
__global__ __launch_bounds__(256, 8) void sample_kernel(
    const u8* __restrict__ vproj, const float* __restrict__ offr,
    const float* __restrict__ attw, const float* __restrict__ ref,
    const u32* __restrict__ perm, const u32* __restrict__ total,
    u16* __restrict__ part2) {
  constexpr int Hs[4] = {92, 46, 23, 12};
  constexpr int Ws[4] = {160, 80, 40, 20};
  constexpr int LSI[4] = {0, 14720, 18400, 19320};
  const int idx = blockIdx.x * 4 + (threadIdx.x >> 6);
  if (idx >= (int)*total) return;
  const u32 item = perm[idx];
  const int c = item >> 16;
  const int z = (item >> 14) & 3;
  const int q = item & 0x3fff;
  const int lane = threadIdx.x & 63;
  const int h = lane >> 3;
  const int pp = (lane >> 2) & 1;
  const int d0 = (lane & 3) * 8;

  const float* rc = ref + ((size_t)c * NQ + q) * 8 + z * 2;
  const float rx = rc[0], ry = rc[1];
  const float* offq = offr + (size_t)q * 512 + z * 128 + h * 16;
  const float* attq = attw + (size_t)q * 256 + z * 64 + h * 8;
  const u8* vch = vproj + ((size_t)c * HEADS + h) * NV * 32 + d0;

  f32x2 acc2[4] = {};
#pragma unroll
  for (int l = 0; l < LEVELS; ++l) {
    const int W = Ws[l], H = Hs[l];
    const u8* vl = vch + (size_t)LSI[l] * 32;
    float2 o = *(const float2*)&offq[l * 4 + pp * 2];
    float a = attq[l * 2 + pp];
    float x = rx * (float)W + o.x - 0.5f;
    float y = ry * (float)H + o.y - 0.5f;
    float x0f = floorf(x), y0f = floorf(y);
    float lx = x - x0f, ly = y - y0f;
    int x0 = (int)x0f, y0 = (int)y0f;
    float fx0 = (x0 >= 0 && x0 < W) ? 1.f : 0.f;
    float fx1 = (x0 >= -1 && x0 < W - 1) ? 1.f : 0.f;
    float fy0 = (y0 >= 0 && y0 < H) ? 1.f : 0.f;
    float fy1 = (y0 >= -1 && y0 < H - 1) ? 1.f : 0.f;
    int x0c = min(max(x0, 0), W - 1);
    int x1c = min(max(x0 + 1, 0), W - 1);
    int y0c = min(max(y0, 0), H - 1);
    int y1c = min(max(y0 + 1, 0), H - 1);
    uint2 v00 = *(const uint2*)(vl + (size_t)(y0c * W + x0c) * 32);
    uint2 v01 = *(const uint2*)(vl + (size_t)(y0c * W + x1c) * 32);
    uint2 v10 = *(const uint2*)(vl + (size_t)(y1c * W + x0c) * 32);
    uint2 v11 = *(const uint2*)(vl + (size_t)(y1c * W + x1c) * 32);
    float c00 = a * (1.f - lx) * (1.f - ly) * fx0 * fy0;
    float c01 = a * lx * (1.f - ly) * fx1 * fy0;
    float c10 = a * (1.f - lx) * ly * fx0 * fy1;
    float c11 = a * lx * ly * fx1 * fy1;
#pragma unroll
    for (int half = 0; half < 2; ++half) {
      u32 w00 = half ? v00.y : v00.x, w01 = half ? v01.y : v01.x;
      u32 w10 = half ? v10.y : v10.x, w11 = half ? v11.y : v11.x;
      f32x2 gA0 = __builtin_amdgcn_cvt_pk_f32_fp8(w00, false);
      f32x2 gA1 = __builtin_amdgcn_cvt_pk_f32_fp8(w00, true);
      f32x2 gB0 = __builtin_amdgcn_cvt_pk_f32_fp8(w01, false);
      f32x2 gB1 = __builtin_amdgcn_cvt_pk_f32_fp8(w01, true);
      f32x2 gC0 = __builtin_amdgcn_cvt_pk_f32_fp8(w10, false);
      f32x2 gC1 = __builtin_amdgcn_cvt_pk_f32_fp8(w10, true);
      f32x2 gD0 = __builtin_amdgcn_cvt_pk_f32_fp8(w11, false);
      f32x2 gD1 = __builtin_amdgcn_cvt_pk_f32_fp8(w11, true);
      int b = half * 2;
      acc2[b + 0] += gA0 * c00 + gB0 * c01 + gC0 * c10 + gD0 * c11;
      acc2[b + 1] += gA1 * c00 + gB1 * c01 + gC1 * c10 + gD1 * c11;
    }
  }
  float accs[8] = {acc2[0].x, acc2[0].y, acc2[1].x, acc2[1].y,
                   acc2[2].x, acc2[2].y, acc2[3].x, acc2[3].y};
#pragma unroll
  for (int d = 0; d < 8; ++d) accs[d] += __shfl_xor(accs[d], 4);
  if (pp == 0) {
    u16 o[8];
#pragma unroll
    for (int d = 0; d < 8; ++d) o[d] = f2bf(accs[d]);
    short8v* sp = (short8v*)&part2[((size_t)(z * CAMS + c) * NQ + q) * EMBED + h * 32 + d0];
    __builtin_nontemporal_store(*(short8v*)o, sp);
  }
}

// ------- masked cam+z reduce (bf16 partials) + /count + bf16 pad: sbf(MQ_PAD,256) -------
__global__ void reduce_kernel(const u16* __restrict__ part2, const unsigned char* __restrict__ m,
                              const float* __restrict__ cinv, u16* __restrict__ sbf) {
  int i = blockIdx.x * blockDim.x + threadIdx.x;
  if (i >= MQ_PAD * 32) return;
  int row = i >> 5;
  int col = (i & 31) * 8;
  u16 o[8];
  if (row < NQ) {
    float s[8] = {};
    for (int c = 0; c < CAMS; ++c) {
      if (!m[c * NQ + row]) continue;
#pragma unroll
      for (int z = 0; z < 4; ++z) {
        const short8v* pp = (const short8v*)&part2[((size_t)(z * CAMS + c) * NQ + row) * EMBED + col];
        short8v v = __builtin_nontemporal_load(pp);
#pragma unroll
        for (int j = 0; j < 8; ++j) s[j] += bf2f((u16)v[j]);
      }
    }
    float sc = cinv[row];
#pragma unroll
    for (int j = 0; j < 8; ++j) o[j] = f2bf(s[j] * sc);
  } else {
#pragma unroll
    for (int j = 0; j < 8; ++j) o[j] = 0;
  }
  *(short8v*)&sbf[(size_t)row * 256 + col] = *(short8v*)o;
}

extern "C" void kernel_launch(void* const* d_in, const int* in_sizes, int n_in,
                              void* d_out, int out_size, void* d_ws, size_t ws_size,
                              hipStream_t stream) {
  const float* query     = (const float*)d_in[0];
  const float* query_pos = (const float*)d_in[1];
  const float* value     = (const float*)d_in[2];
  const float* refpts    = (const float*)d_in[3];
  const int*   bev       = (const int*)d_in[4];
  const float* Wv   = (const float*)d_in[7];
  const float* bv   = (const float*)d_in[8];
  const float* Woff = (const float*)d_in[9];
  const float* boff = (const float*)d_in[10];
  const float* Watt = (const float*)d_in[11];
  const float* batt = (const float*)d_in[12];
  const float* Wout = (const float*)d_in[13];
  const float* bout = (const float*)d_in[14];
  float* out = (float*)d_out;

  char* ws = (char*)d_ws;
  auto alloc = [&](size_t bytes) {
    char* p = ws;
    ws += (bytes + 255) & ~(size_t)255;
    return p;
  };
  u16*   qbf   = (u16*)alloc((size_t)MQ_PAD * 256 * 2);
  u16*   sbf   = (u16*)alloc((size_t)MQ_PAD * 256 * 2);
  u16*   WvT   = (u16*)alloc((size_t)256 * 256 * 2);
  u16*   WqT   = (u16*)alloc((size_t)768 * 256 * 2);   // permuted (z-major output cols)
  u16*   WoutT = (u16*)alloc((size_t)256 * 256 * 2);
  float* catb  = (float*)alloc((size_t)768 * 4);
  float* offr  = (float*)alloc((size_t)MQ_PAD * 512 * 4);
  float* attw  = (float*)alloc((size_t)MQ_PAD * 256 * 4);
  u8*    vproj = (u8*)alloc((size_t)CAMS * NV * EMBED);
  u16*   part2 = (u16*)alloc((size_t)4 * CAMS * NQ * EMBED * 2);
  float* cinv  = (float*)alloc((size_t)NQ * 4);
  unsigned char* msk = (unsigned char*)alloc((size_t)CAMS * NQ);
  u32*   hist  = (u32*)alloc((size_t)NBUCK * 4);
  u32*   cursor= (u32*)alloc((size_t)NBUCK * 4);
  u32*   total = (u32*)alloc(256);
  u32*   perm  = (u32*)alloc((size_t)MAXITEMS * 4);

  hipMemsetAsync(hist, 0, NBUCK * 4, stream);

  conv_bf16_kernel<<<(MQ_PAD * 32 + 255) / 256, 256, 0, stream>>>(query, query_pos, qbf, NQ, MQ_PAD);
  mask_kernel<<<(NQ + 255) / 256, 256, 0, stream>>>(bev, refpts, msk, cinv, hist);
  transpose_wq_kernel<<<(768 * 256 + 255) / 256, 256, 0, stream>>>(Woff, Watt, boff, batt, WqT, catb);
  transpose_w_kernel<<<256, 256, 0, stream>>>(Wv, WvT, 256);
  transpose_w_kernel<<<256, 256, 0, stream>>>(Wout, WoutT, 256);

  scan_kernel<<<1, NBUCK, 0, stream>>>(hist, cursor, total);
  scatter_kernel<<<(NQ + 255) / 256, 256, 0, stream>>>(refpts, msk, cursor, perm);

  dim3 gQ(768 / 128, MQ_PAD / 128);
  gemm_mfma<<<gQ, 256, 0, stream>>>(qbf, WqT, catb, nullptr, offr, attw, NQ, 768, 3);
  softmax_kernel<<<(NQ * HEADS + 255) / 256, 256, 0, stream>>>(attw);

  gemm_wv_f32<<<MV_PAD / 128, 512, 0, stream>>>(value, WvT, bv, vproj, CAMS * NV);

  sample_kernel<<<MAXITEMS / 4, 256, 0, stream>>>(vproj, offr, attw, refpts, perm, total, part2);

  reduce_kernel<<<(MQ_PAD * 32 + 255) / 256, 256, 0, stream>>>(part2, msk, cinv, sbf);
  dim3 gOut(256 / 128, MQ_PAD / 128);
  gemm_mfma<<<gOut, 256, 0, stream>>>(sbf, WoutT, bout, query, out, nullptr, NQ, 256, 2);
}

// Round 19
// 409.822 us; speedup vs baseline: 1.1659x; 1.0458x over previous
//
#include <hip/hip_runtime.h>
#include <hip/hip_bf16.h>

constexpr int NQ = 10000, NV = 19560, CAMS = 6, EMBED = 256, HEADS = 8,
              HEAD_DIM = 32, LEVELS = 4, POINTS = 8;
constexpr int MQ_PAD = 10112;          // 79 * 128
constexpr int MV_PAD = 117376;         // 917 * 128
constexpr int NBUCK = CAMS * 128;      // 16x8 tiles per cam
constexpr int MAXITEMS = CAMS * NQ * 4;

typedef unsigned int u32;
typedef unsigned short u16;
typedef unsigned char u8;
typedef __attribute__((ext_vector_type(8))) short short8v;
typedef __attribute__((ext_vector_type(4))) float f32x4;
typedef __attribute__((ext_vector_type(2))) float f32x2;
typedef __attribute__((ext_vector_type(2))) unsigned int u32x2;

__device__ inline u16 f2bf(float f) {
  __hip_bfloat16 b = __float2bfloat16(f);
  return *(u16*)&b;
}
__device__ inline float bf2f(u16 v) { union { u32 i; float f; } x; x.i = (u32)v << 16; return x.f; }

// ---------------- fp32 -> bf16 row-padded convert (optional fused add) ----------------
__global__ void conv_bf16_kernel(const float* __restrict__ a, const float* __restrict__ b,
                                 u16* __restrict__ dst, int M, int Mpad) {
  int i = blockIdx.x * blockDim.x + threadIdx.x;
  if (i >= Mpad * 32) return;
  int row = i >> 5;
  int col = (i & 31) * 8;
  u16 o[8];
  if (row < M) {
    const float* pa = a + (size_t)row * 256 + col;
#pragma unroll
    for (int j = 0; j < 8; ++j) {
      float v = pa[j];
      if (b) v += b[(size_t)row * 256 + col + j];
      o[j] = f2bf(v);
    }
  } else {
#pragma unroll
    for (int j = 0; j < 8; ++j) o[j] = 0;
  }
  *(short8v*)&dst[(size_t)row * 256 + col] = *(short8v*)o;
}

// ------- fused weight transposes: WqT (permuted, 768 rows) + WvT (256) + WoutT (256) + catb -------
__device__ inline int orig_off_col(int j) {          // j in [0,512)
  int z = (j >> 7) & 3, h = (j >> 4) & 7, l = (j >> 2) & 3, pi = (j >> 1) & 1, xy = j & 1;
  return h * 64 + l * 16 + (z + 4 * pi) * 2 + xy;
}
__device__ inline int orig_att_col(int j) {          // j in [0,256)
  int z = (j >> 6) & 3, h = (j >> 3) & 7, l = (j >> 1) & 3, pi = j & 1;
  return h * 32 + l * 8 + (z + 4 * pi);
}
__global__ void transpose_all_kernel(
    const float* __restrict__ Woff, const float* __restrict__ Watt,
    const float* __restrict__ Wv, const float* __restrict__ Wout,
    const float* __restrict__ boff, const float* __restrict__ batt,
    u16* __restrict__ WqT, u16* __restrict__ WvT, u16* __restrict__ WoutT,
    float* __restrict__ catb) {
  int g = blockIdx.x * blockDim.x + threadIdx.x;
  if (g >= 1280 * 256) return;
  int j = g >> 8, k = g & 255;
  if (j < 512) {
    WqT[(size_t)j * 256 + k] = f2bf(Woff[(size_t)k * 512 + orig_off_col(j)]);
    if (k == 0) catb[j] = boff[orig_off_col(j)];
  } else if (j < 768) {
    WqT[(size_t)j * 256 + k] = f2bf(Watt[(size_t)k * 256 + orig_att_col(j - 512)]);
    if (k == 0) catb[j] = batt[orig_att_col(j - 512)];
  } else if (j < 1024) {
    WvT[(size_t)(j - 768) * 256 + k] = f2bf(Wv[(size_t)k * 256 + (j - 768)]);
  } else {
    WoutT[(size_t)(j - 1024) * 256 + k] = f2bf(Wout[(size_t)k * 256 + (j - 1024)]);
  }
}

// ---------------- bucket key ----------------
__device__ inline int buck_key(int c, float rx, float ry) {
  int tx = min(max((int)(rx * 16.f), 0), 15);
  int ty = min(max((int)(ry * 8.f), 0), 7);
  return c * 128 + ty * 16 + tx;
}

// ---------------- per-(cam,q) mask + 1/count + fused histogram ----------------
__global__ void mask_kernel(const int* __restrict__ bev, const float* __restrict__ ref,
                            unsigned char* __restrict__ m, float* __restrict__ cinv,
                            u32* __restrict__ hist) {
  int q = blockIdx.x * blockDim.x + threadIdx.x;
  if (q >= NQ) return;
  int cnt = 0;
  for (int c = 0; c < CAMS; ++c) {
    int any = 0;
    for (int z = 0; z < 4; ++z) any |= bev[((size_t)c * NQ + q) * 4 + z];
    m[c * NQ + q] = (unsigned char)(any != 0);
    cnt += (any != 0);
    if (any) {
      const float* rc = ref + ((size_t)c * NQ + q) * 8;
#pragma unroll
      for (int z = 0; z < 4; ++z)
        atomicAdd(&hist[buck_key(c, rc[z * 2], rc[z * 2 + 1])], 1u);
    }
  }
  cinv[q] = 1.0f / (float)(cnt > 0 ? cnt : 1);
}

// ---------------- exclusive scan over NBUCK buckets (one block) ----------------
__global__ void scan_kernel(const u32* __restrict__ hist, u32* __restrict__ cursor,
                            u32* __restrict__ total) {
  __shared__ u32 tmp[NBUCK];
  int t = threadIdx.x;
  u32 v = hist[t];
  tmp[t] = v;
  __syncthreads();
  for (int d = 1; d < NBUCK; d <<= 1) {
    u32 add = (t >= d) ? tmp[t - d] : 0;
    __syncthreads();
    tmp[t] += add;
    __syncthreads();
  }
  cursor[t] = tmp[t] - v;   // exclusive
  if (t == NBUCK - 1) *total = tmp[t];
}

// ---------------- scatter items into perm (sorted by bucket) ----------------
__global__ void scatter_kernel(const float* __restrict__ ref, const unsigned char* __restrict__ m,
                               u32* __restrict__ cursor, u32* __restrict__ perm) {
  int q = blockIdx.x * blockDim.x + threadIdx.x;
  if (q >= NQ) return;
  for (int c = 0; c < CAMS; ++c) {
    if (!m[c * NQ + q]) continue;
    const float* rc = ref + ((size_t)c * NQ + q) * 8;
#pragma unroll
    for (int z = 0; z < 4; ++z) {
      u32 pos = atomicAdd(&cursor[buck_key(c, rc[z * 2], rc[z * 2 + 1])], 1u);
      perm[pos] = ((u32)c << 16) | ((u32)z << 14) | (u32)q;
    }
  }
}

// ---------------- bf16 MFMA GEMM (128x128 tile, 256 thr) ----------------
// mode 0: fp32 out. mode 2: fp32 out + add. mode 3: coalesced split.
__global__ __launch_bounds__(256) void gemm_mfma(
    const u16* __restrict__ A, const u16* __restrict__ Bt,
    const float* __restrict__ bias, const float* __restrict__ add,
    void* __restrict__ Cout, void* __restrict__ Cout2, int M, int N, int mode) {
  constexpr int K = 256, BK = 64;
  __shared__ u16 As[128 * BK];
  __shared__ u16 Bs[128 * BK];
  const int tid = threadIdx.x;
  const int lane = tid & 63, w = tid >> 6;
  const int wr = w >> 1, wc = w & 1;
  const int row0 = blockIdx.y * 128, col0 = blockIdx.x * 128;
  f32x4 acc[4][4] = {};

  for (int k0 = 0; k0 < K; k0 += BK) {
    short8v areg[4], breg[4];
#pragma unroll
    for (int j = 0; j < 4; ++j) {
      int e = tid + j * 256;
      int r = e >> 3, cb = (e & 7) * 16;
      areg[j] = *(const short8v*)((const char*)A + ((size_t)(row0 + r) * K + k0) * 2 + cb);
      breg[j] = *(const short8v*)((const char*)Bt + ((size_t)(col0 + r) * K + k0) * 2 + cb);
    }
    __syncthreads();
#pragma unroll
    for (int j = 0; j < 4; ++j) {
      int e = tid + j * 256;
      int r = e >> 3, cb = (e & 7) * 16;
      int sw = cb ^ ((r & 7) << 4);
      *(short8v*)((char*)As + r * 128 + sw) = areg[j];
      *(short8v*)((char*)Bs + r * 128 + sw) = breg[j];
    }
    __syncthreads();
#pragma unroll
    for (int kk = 0; kk < 2; ++kk) {
      short8v af[4], bf[4];
#pragma unroll
      for (int m = 0; m < 4; ++m) {
        int r = wr * 64 + m * 16 + (lane & 15);
        int cb = kk * 64 + (lane >> 4) * 16;
        af[m] = *(const short8v*)((const char*)As + r * 128 + (cb ^ ((r & 7) << 4)));
      }
#pragma unroll
      for (int n = 0; n < 4; ++n) {
        int r = wc * 64 + n * 16 + (lane & 15);
        int cb = kk * 64 + (lane >> 4) * 16;
        bf[n] = *(const short8v*)((const char*)Bs + r * 128 + (cb ^ ((r & 7) << 4)));
      }
#pragma unroll
      for (int m = 0; m < 4; ++m)
#pragma unroll
        for (int n = 0; n < 4; ++n)
          acc[m][n] = __builtin_amdgcn_mfma_f32_16x16x32_bf16(af[m], bf[n], acc[m][n], 0, 0, 0);
    }
  }

#pragma unroll
  for (int m = 0; m < 4; ++m) {
    int rowb = row0 + wr * 64 + m * 16 + (lane >> 4) * 4;
#pragma unroll
    for (int r = 0; r < 4; ++r) {
      int rr = rowb + r;
      if (rr >= M) continue;
#pragma unroll
      for (int n = 0; n < 4; ++n) {
        int col = col0 + wc * 64 + n * 16 + (lane & 15);
        float v = acc[m][n][r] + bias[col];
        if (mode == 0) {
          ((float*)Cout)[(size_t)rr * N + col] = v;
        } else if (mode == 2) {
          ((float*)Cout)[(size_t)rr * N + col] = v + add[(size_t)rr * N + col];
        } else {
          if (col < 512) ((float*)Cout)[(size_t)rr * 512 + col] = v;
          else           ((float*)Cout2)[(size_t)rr * 256 + (col - 512)] = v;
        }
      }
    }
  }
}

// ------- Wv GEMM: 512 thr, tile 128x256 (full N) so A is staged ONCE. -------
__global__ __launch_bounds__(512) void gemm_wv_f32(
    const float* __restrict__ A, const u16* __restrict__ Bt,
    const float* __restrict__ bias, u8* __restrict__ Cout, int M) {
  constexpr int K = 256, BK = 64;
  __shared__ u16 As[128 * BK];   // 16 KB
  __shared__ u16 Bs[256 * BK];   // 32 KB
  const int tid = threadIdx.x;
  const int lane = tid & 63, w = tid >> 6;
  const int wr = w >> 2, wc = w & 3;
  const int row0 = blockIdx.x * 128;
  f32x4 acc[4][4] = {};

  for (int k0 = 0; k0 < K; k0 += BK) {
    short8v areg[2], breg[4];
#pragma unroll
    for (int j = 0; j < 2; ++j) {
      int e = tid + j * 512;
      int r = e >> 3, co = (e & 7) * 8;
      u16 tmp[8];
      if (row0 + r < M) {
        const float* src = A + (size_t)(row0 + r) * K + k0 + co;
        float4 f0 = *(const float4*)src;
        float4 f1 = *(const float4*)(src + 4);
        tmp[0] = f2bf(f0.x); tmp[1] = f2bf(f0.y); tmp[2] = f2bf(f0.z); tmp[3] = f2bf(f0.w);
        tmp[4] = f2bf(f1.x); tmp[5] = f2bf(f1.y); tmp[6] = f2bf(f1.z); tmp[7] = f2bf(f1.w);
      } else {
#pragma unroll
        for (int t = 0; t < 8; ++t) tmp[t] = 0;
      }
      areg[j] = *(short8v*)tmp;
    }
#pragma unroll
    for (int j = 0; j < 4; ++j) {
      int e = tid + j * 512;
      int r = e >> 3, cb = (e & 7) * 16;
      breg[j] = *(const short8v*)((const char*)Bt + ((size_t)r * K + k0) * 2 + cb);
    }
    __syncthreads();
#pragma unroll
    for (int j = 0; j < 2; ++j) {
      int e = tid + j * 512;
      int r = e >> 3, cb = (e & 7) * 16;
      *(short8v*)((char*)As + r * 128 + (cb ^ ((r & 7) << 4))) = areg[j];
    }
#pragma unroll
    for (int j = 0; j < 4; ++j) {
      int e = tid + j * 512;
      int r = e >> 3, cb = (e & 7) * 16;
      *(short8v*)((char*)Bs + r * 128 + (cb ^ ((r & 7) << 4))) = breg[j];
    }
    __syncthreads();
#pragma unroll
    for (int kk = 0; kk < 2; ++kk) {
      short8v af[4], bf[4];
#pragma unroll
      for (int m = 0; m < 4; ++m) {
        int r = wr * 64 + m * 16 + (lane & 15);
        int cb = kk * 64 + (lane >> 4) * 16;
        af[m] = *(const short8v*)((const char*)As + r * 128 + (cb ^ ((r & 7) << 4)));
      }
#pragma unroll
      for (int n = 0; n < 4; ++n) {
        int r = wc * 64 + n * 16 + (lane & 15);
        int cb = kk * 64 + (lane >> 4) * 16;
        bf[n] = *(const short8v*)((const char*)Bs + r * 128 + (cb ^ ((r & 7) << 4)));
      }
#pragma unroll
      for (int m = 0; m < 4; ++m)
#pragma unroll
        for (int n = 0; n < 4; ++n)
          acc[m][n] = __builtin_amdgcn_mfma_f32_16x16x32_bf16(af[m], bf[n], acc[m][n], 0, 0, 0);
    }
  }

#pragma unroll
  for (int m = 0; m < 4; ++m) {
    int rowb = row0 + wr * 64 + m * 16 + (lane >> 4) * 4;
#pragma unroll
    for (int r = 0; r < 4; ++r) {
      int rr = rowb + r;
      if (rr >= M) continue;
      int cam = rr / NV;
      int px = rr - cam * NV;
#pragma unroll
      for (int n = 0; n < 4; ++n) {
        int col = wc * 64 + n * 16 + (lane & 15);
        float v = acc[m][n][r] + bias[col];
        int h = col >> 5, d = col & 31;
        int pk = __builtin_amdgcn_cvt_pk_fp8_f32(v, v, 0, false);
        Cout[(((size_t)cam * HEADS + h) * NV + px) * 32 + d] = (u8)(pk & 0xff);
      }
    }
  }
}

// ---------------- softmax over 32 (per q,head), z-major layout ----------------
__global__ void softmax_kernel(float* __restrict__ att) {
  int r = blockIdx.x * blockDim.x + threadIdx.x;
  if (r >= NQ * HEADS) return;
  int q = r >> 3, h = r & 7;
  float* base = att + (size_t)q * 256 + h * 8;
  float v[32];
  float mx = -1e30f;
  int n = 0;
#pragma unroll
  for (int z = 0; z < 4; ++z)
#pragma unroll
    for (int l = 0; l < 4; ++l)
#pragma unroll
      for (int pi = 0; pi < 2; ++pi) {
        float x = base[z * 64 + l * 2 + pi];
        v[n++] = x;
        mx = fmaxf(mx, x);
      }
  float sm = 0.f;
#pragma unroll
  for (int i = 0; i < 32; ++i) { v[i] = expf(v[i] - mx); sm += v[i]; }
  float inv = 1.0f / sm;
  n = 0;
#pragma unroll
  for (int z = 0; z < 4; ++z)
#pragma unroll
    for (int l = 0; l < 4; ++l)
#pragma unroll
      for (int pi = 0; pi < 2; ++pi)
        base[z * 64 + l * 2 + pi] = v[n++] * inv;
}

// ---------------- deformable sampling: one wave per SORTED (cam,q,z) item ----------------
// lane = h|pp|dl, f32x2 pk-fma, full level unroll. fp8 partial stores (u32x2/lane-group).
__global__ __launch_bounds__(256, 8) void sample_kernel(
    const u8* __restrict__ vproj, const float* __restrict__ offr,
    const float* __restrict__ attw, const float* __restrict__ ref,
    const u32* __restrict__ perm, const u32* __restrict__ total,
    u8* __restrict__ part2) {
  constexpr int Hs[4] = {92, 46, 23, 12};
  constexpr int Ws[4] = {160, 80, 40, 20};
  constexpr int LSI[4] = {0, 14720, 18400, 19320};
  const int idx = blockIdx.x * 4 + (threadIdx.x >> 6);
  if (idx >= (int)*total) return;
  const u32 item = perm[idx];
  const int c = item >> 16;
  const int z = (item >> 14) & 3;
  const int q = item & 0x3fff;
  const int lane = threadIdx.x & 63;
  const int h = lane >> 3;
  const int pp = (lane >> 2) & 1;
  const int d0 = (lane & 3) * 8;

  const float* rc = ref + ((size_t)c * NQ + q) * 8 + z * 2;
  const float rx = rc[0], ry = rc[1];
  const float* offq = offr + (size_t)q * 512 + z * 128 + h * 16;
  const float* attq = attw + (size_t)q * 256 + z * 64 + h * 8;
  const u8* vch = vproj + ((size_t)c * HEADS + h) * NV * 32 + d0;

  f32x2 acc2[4] = {};
#pragma unroll
  for (int l = 0; l < LEVELS; ++l) {
    const int W = Ws[l], H = Hs[l];
    const u8* vl = vch + (size_t)LSI[l] * 32;
    float2 o = *(const float2*)&offq[l * 4 + pp * 2];
    float a = attq[l * 2 + pp];
    float x = rx * (float)W + o.x - 0.5f;
    float y = ry * (float)H + o.y - 0.5f;
    float x0f = floorf(x), y0f = floorf(y);
    float lx = x - x0f, ly = y - y0f;
    int x0 = (int)x0f, y0 = (int)y0f;
    float fx0 = (x0 >= 0 && x0 < W) ? 1.f : 0.f;
    float fx1 = (x0 >= -1 && x0 < W - 1) ? 1.f : 0.f;
    float fy0 = (y0 >= 0 && y0 < H) ? 1.f : 0.f;
    float fy1 = (y0 >= -1 && y0 < H - 1) ? 1.f : 0.f;
    int x0c = min(max(x0, 0), W - 1);
    int x1c = min(max(x0 + 1, 0), W - 1);
    int y0c = min(max(y0, 0), H - 1);
    int y1c = min(max(y0 + 1, 0), H - 1);
    uint2 v00 = *(const uint2*)(vl + (size_t)(y0c * W + x0c) * 32);
    uint2 v01 = *(const uint2*)(vl + (size_t)(y0c * W + x1c) * 32);
    uint2 v10 = *(const uint2*)(vl + (size_t)(y1c * W + x0c) * 32);
    uint2 v11 = *(const uint2*)(vl + (size_t)(y1c * W + x1c) * 32);
    float c00 = a * (1.f - lx) * (1.f - ly) * fx0 * fy0;
    float c01 = a * lx * (1.f - ly) * fx1 * fy0;
    float c10 = a * (1.f - lx) * ly * fx0 * fy1;
    float c11 = a * lx * ly * fx1 * fy1;
#pragma unroll
    for (int half = 0; half < 2; ++half) {
      u32 w00 = half ? v00.y : v00.x, w01 = half ? v01.y : v01.x;
      u32 w10 = half ? v10.y : v10.x, w11 = half ? v11.y : v11.x;
      f32x2 gA0 = __builtin_amdgcn_cvt_pk_f32_fp8(w00, false);
      f32x2 gA1 = __builtin_amdgcn_cvt_pk_f32_fp8(w00, true);
      f32x2 gB0 = __builtin_amdgcn_cvt_pk_f32_fp8(w01, false);
      f32x2 gB1 = __builtin_amdgcn_cvt_pk_f32_fp8(w01, true);
      f32x2 gC0 = __builtin_amdgcn_cvt_pk_f32_fp8(w10, false);
      f32x2 gC1 = __builtin_amdgcn_cvt_pk_f32_fp8(w10, true);
      f32x2 gD0 = __builtin_amdgcn_cvt_pk_f32_fp8(w11, false);
      f32x2 gD1 = __builtin_amdgcn_cvt_pk_f32_fp8(w11, true);
      int b = half * 2;
      acc2[b + 0] += gA0 * c00 + gB0 * c01 + gC0 * c10 + gD0 * c11;
      acc2[b + 1] += gA1 * c00 + gB1 * c01 + gC1 * c10 + gD1 * c11;
    }
  }
  float accs[8] = {acc2[0].x, acc2[0].y, acc2[1].x, acc2[1].y,
                   acc2[2].x, acc2[2].y, acc2[3].x, acc2[3].y};
#pragma unroll
  for (int d = 0; d < 8; ++d) accs[d] += __shfl_xor(accs[d], 4);
  if (pp == 0) {
    u32 w0 = 0, w1 = 0;
    w0 = __builtin_amdgcn_cvt_pk_fp8_f32(accs[0], accs[1], 0, false);
    w0 = __builtin_amdgcn_cvt_pk_fp8_f32(accs[2], accs[3], w0, true);
    w1 = __builtin_amdgcn_cvt_pk_fp8_f32(accs[4], accs[5], 0, false);
    w1 = __builtin_amdgcn_cvt_pk_fp8_f32(accs[6], accs[7], w1, true);
    u32x2 pk = {w0, w1};
    __builtin_nontemporal_store(pk, (u32x2*)&part2[((size_t)(z * CAMS + c) * NQ + q) * EMBED + h * 32 + d0]);
  }
}

// ------- masked cam+z reduce (fp8 partials) + /count + bf16 pad: sbf(MQ_PAD,256) -------
__global__ void reduce_kernel(const u8* __restrict__ part2, const unsigned char* __restrict__ m,
                              const float* __restrict__ cinv, u16* __restrict__ sbf) {
  int i = blockIdx.x * blockDim.x + threadIdx.x;
  if (i >= MQ_PAD * 32) return;
  int row = i >> 5;
  int col = (i & 31) * 8;
  u16 o[8];
  if (row < NQ) {
    f32x2 s[4] = {};
    for (int c = 0; c < CAMS; ++c) {
      if (!m[c * NQ + row]) continue;
#pragma unroll
      for (int z = 0; z < 4; ++z) {
        const u32x2* pp = (const u32x2*)&part2[((size_t)(z * CAMS + c) * NQ + row) * EMBED + col];
        u32x2 v = __builtin_nontemporal_load(pp);
        s[0] += __builtin_amdgcn_cvt_pk_f32_fp8(v.x, false);
        s[1] += __builtin_amdgcn_cvt_pk_f32_fp8(v.x, true);
        s[2] += __builtin_amdgcn_cvt_pk_f32_fp8(v.y, false);
        s[3] += __builtin_amdgcn_cvt_pk_f32_fp8(v.y, true);
      }
    }
    float sc = cinv[row];
#pragma unroll
    for (int j = 0; j < 4; ++j) {
      o[2 * j + 0] = f2bf(s[j].x * sc);
      o[2 * j + 1] = f2bf(s[j].y * sc);
    }
  } else {
#pragma unroll
    for (int j = 0; j < 8; ++j) o[j] = 0;
  }
  *(short8v*)&sbf[(size_t)row * 256 + col] = *(short8v*)o;
}

extern "C" void kernel_launch(void* const* d_in, const int* in_sizes, int n_in,
                              void* d_out, int out_size, void* d_ws, size_t ws_size,
                              hipStream_t stream) {
  const float* query     = (const float*)d_in[0];
  const float* query_pos = (const float*)d_in[1];
  const float* value     = (const float*)d_in[2];
  const float* refpts    = (const float*)d_in[3];
  const int*   bev       = (const int*)d_in[4];
  const float* Wv   = (const float*)d_in[7];
  const float* bv   = (const float*)d_in[8];
  const float* Woff = (const float*)d_in[9];
  const float* boff = (const float*)d_in[10];
  const float* Watt = (const float*)d_in[11];
  const float* batt = (const float*)d_in[12];
  const float* Wout = (const float*)d_in[13];
  const float* bout = (const float*)d_in[14];
  float* out = (float*)d_out;

  char* ws = (char*)d_ws;
  auto alloc = [&](size_t bytes) {
    char* p = ws;
    ws += (bytes + 255) & ~(size_t)255;
    return p;
  };
  u16*   qbf   = (u16*)alloc((size_t)MQ_PAD * 256 * 2);
  u16*   sbf   = (u16*)alloc((size_t)MQ_PAD * 256 * 2);
  u16*   WvT   = (u16*)alloc((size_t)256 * 256 * 2);
  u16*   WqT   = (u16*)alloc((size_t)768 * 256 * 2);   // permuted (z-major output cols)
  u16*   WoutT = (u16*)alloc((size_t)256 * 256 * 2);
  float* catb  = (float*)alloc((size_t)768 * 4);
  float* offr  = (float*)alloc((size_t)MQ_PAD * 512 * 4);
  float* attw  = (float*)alloc((size_t)MQ_PAD * 256 * 4);
  u8*    vproj = (u8*)alloc((size_t)CAMS * NV * EMBED);
  u8*    part2 = (u8*)alloc((size_t)4 * CAMS * NQ * EMBED);
  float* cinv  = (float*)alloc((size_t)NQ * 4);
  unsigned char* msk = (unsigned char*)alloc((size_t)CAMS * NQ);
  u32*   hist  = (u32*)alloc((size_t)NBUCK * 4);
  u32*   cursor= (u32*)alloc((size_t)NBUCK * 4);
  u32*   total = (u32*)alloc(256);
  u32*   perm  = (u32*)alloc((size_t)MAXITEMS * 4);

  hipMemsetAsync(hist, 0, NBUCK * 4, stream);

  conv_bf16_kernel<<<(MQ_PAD * 32 + 255) / 256, 256, 0, stream>>>(query, query_pos, qbf, NQ, MQ_PAD);
  mask_kernel<<<(NQ + 255) / 256, 256, 0, stream>>>(bev, refpts, msk, cinv, hist);
  transpose_all_kernel<<<(1280 * 256 + 255) / 256, 256, 0, stream>>>(
      Woff, Watt, Wv, Wout, boff, batt, WqT, WvT, WoutT, catb);

  scan_kernel<<<1, NBUCK, 0, stream>>>(hist, cursor, total);
  scatter_kernel<<<(NQ + 255) / 256, 256, 0, stream>>>(refpts, msk, cursor, perm);

  dim3 gQ(768 / 128, MQ_PAD / 128);
  gemm_mfma<<<gQ, 256, 0, stream>>>(qbf, WqT, catb, nullptr, offr, attw, NQ, 768, 3);
  softmax_kernel<<<(NQ * HEADS + 255) / 256, 256, 0, stream>>>(attw);

  gemm_wv_f32<<<MV_PAD / 128, 512, 0, stream>>>(value, WvT, bv, vproj, CAMS * NV);

  sample_kernel<<<MAXITEMS / 4, 256, 0, stream>>>(vproj, offr, attw, refpts, perm, total, part2);

  reduce_kernel<<<(MQ_PAD * 32 + 255) / 256, 256, 0, stream>>>(part2, msk, cinv, sbf);
  dim3 gOut(256 / 128, MQ_PAD / 128);
  gemm_mfma<<<gOut, 256, 0, stream>>>(sbf, WoutT, bout, query, out, nullptr, NQ, 256, 2);
}